// Round 14
// baseline (893.747 us; speedup 1.0000x reference)
//
#include <hip/hip_runtime.h>
#include <cfloat>
#include <cmath>

// ---------------------------------------------------------------------------
// Round 31: channel-interleave d2 ([ci/4][spatial][ci%4]).
// R30 post-mortem: write-halving confirmed for bytes (66->33MB) but dec3 dur
// ~flat (87.4us) -- not write-bound. The model fitting ALL rounds: TA line
// touches. dec3's 16 X-instrs/phase each touch 4 lines (quad = channel
// selects 4 separate 78KB planes; 16-lane groups span 32B) + 32 A lines
// => ~49k lines/CU * 4.5cy = 220k cy = 87us. R29 regrouped loads without
// changing lines -> null, as observed.
// Fix: d2 interleaved by 4 channels. dec3: one dwordx4/lane covers both
// x-taps x all 4 ch; wave footprint/instr = ~136B contiguous = 3 lines vs 4,
// quad-planes gone. dec2: co&3 == r, so each accumulator column stores as
// ONE 8B word instead of 4 scalar plane-scattered stores. Same RNE values,
// same MFMA order, extraction reproduces exact old (x1,x1+1) taps =>
// bit-identical. Halo kernel gets interleave-aware variant.
// Everything else unchanged from R30.
// ---------------------------------------------------------------------------

using f32x4  = __attribute__((ext_vector_type(4))) float;
using bf16x8 = __attribute__((ext_vector_type(8))) short;
typedef float f32x4u __attribute__((ext_vector_type(4), aligned(4)));
typedef unsigned short u16x4u __attribute__((ext_vector_type(4), aligned(4)));
typedef unsigned short u16x8a4 __attribute__((ext_vector_type(8), aligned(4)));

__device__ __forceinline__ unsigned short f32_to_bf16(float f) {
    unsigned int u = __float_as_uint(f);
    u += 0x7fffu + ((u >> 16) & 1u);          // round-to-nearest-even
    return (unsigned short)(u >> 16);
}
__device__ __forceinline__ void split_bf16(float v, unsigned short& h, unsigned short& l) {
    h = f32_to_bf16(v);
    float hf = __uint_as_float((unsigned)h << 16);
    l = f32_to_bf16(v - hf);
}
// truncating bf16 store type (top 16 bits of fp32; NOT RNE)
struct bf16t { unsigned short u; };
__device__ __forceinline__ void store_act(float* p, float v) { *p = v; }
__device__ __forceinline__ void store_act(unsigned short* p, float v) { *p = f32_to_bf16(v); }
__device__ __forceinline__ void store_act(bf16t* p, float v) {
    p->u = (unsigned short)(__float_as_uint(v) >> 16);
}

template <typename V>
__device__ __forceinline__ bf16x8 pack_b(V r0, V r1) {
    bf16x8 b;
    b[0] = (short)r0[0]; b[1] = (short)r0[1]; b[2] = (short)r0[2]; b[3] = (short)r0[3];
    b[4] = (short)r1[0]; b[5] = (short)r1[1]; b[6] = (short)r1[2]; b[7] = (short)r1[3];
    return b;
}

// ---------------- prep: weight hi/lo split (linear; enc1) ----------------
__global__ __launch_bounds__(256)
void prep_split_w(const float* __restrict__ w, short* __restrict__ whi,
                  short* __restrict__ wlo, long total)
{
    long idx = (long)blockIdx.x * blockDim.x + threadIdx.x;
    if (idx >= total) return;
    unsigned short h, l;
    split_bf16(w[idx], h, l);
    whi[idx] = (short)h; wlo[idx] = (short)l;
}

// Fragment-major hi/lo split for enc2/enc3:
//   whi[((s*MT + m)*64 + l)*8 + kk] = hi(w[co*K + korig])
__global__ __launch_bounds__(256)
void prep_split_w_frag(const float* __restrict__ w, short* __restrict__ whi,
                       short* __restrict__ wlo, int CIN, int COUT)
{
    const int K = CIN * 64;
    const int MT = COUT >> 4;
    long total = (long)COUT * K;
    long idx = (long)blockIdx.x * blockDim.x + threadIdx.x;
    if (idx >= total) return;
    int kk = (int)(idx & 7); long r = idx >> 3;
    int l  = (int)(r & 63);  r >>= 6;
    int m  = (int)(r % MT);
    int s  = (int)(r / MT);
    int n16 = l & 15, quad = l >> 4;
    int co = m * 16 + n16;
    int korig = s * 32 + quad * 8 + kk;
    unsigned short h, lo16;
    split_bf16(w[(long)co * K + korig], h, lo16);
    whi[idx] = (short)h; wlo[idx] = (short)lo16;
}

// ---------------- pad input -> hi/lo bf16 pitched planes --------------------
__global__ __launch_bounds__(256)
void pad_input_split(const float* __restrict__ x, unsigned short* __restrict__ xhi,
                     unsigned short* __restrict__ xlo)
{
    const int D = 64, PD = 66, PRX = 68, BC = 6;
    long total = (long)BC * PD * PD * PRX;
    long idx = (long)blockIdx.x * blockDim.x + threadIdx.x;
    if (idx >= total) return;
    int px = (int)(idx % PRX); long t = idx / PRX;
    int py = (int)(t % PD); t /= PD;
    int pz = (int)(t % PD); int c = (int)(t / PD);
    int ix = px - 1, iy = py - 1, iz = pz - 1;
    float v = 0.0f;
    if ((unsigned)ix < (unsigned)D && (unsigned)iy < (unsigned)D && (unsigned)iz < (unsigned)D)
        v = x[(((long)c * D + iz) * D + iy) * D + ix];
    unsigned short h, l;
    split_bf16(v, h, l);
    xhi[idx] = h; xlo[idx] = l;
}

__global__ __launch_bounds__(256)
void zero_halo_ps(unsigned short* __restrict__ p, int C, int PD, int PRX)
{
    long total = (long)C * PD * PD * PRX;
    long idx = (long)blockIdx.x * blockDim.x + threadIdx.x;
    if (idx >= total) return;
    int px = (int)(idx % PRX); long t = idx / PRX;
    int py = (int)(t % PD); t /= PD;
    int pz = (int)(t % PD);
    if (px == 0 || px >= PD - 1 || py == 0 || py == PD - 1 || pz == 0 || pz == PD - 1)
        p[idx] = 0;
}

template <typename T>
__global__ __launch_bounds__(256) void zero_halo_t(T* __restrict__ p, int C, int PD)
{
    long total = (long)C * PD * PD * PD;
    long idx = (long)blockIdx.x * blockDim.x + threadIdx.x;
    if (idx >= total) return;
    int px = (int)(idx % PD); long t = idx / PD;
    int py = (int)(t % PD); t /= PD;
    int pz = (int)(t % PD);
    if (px == 0 || px == PD - 1 || py == 0 || py == PD - 1 || pz == 0 || pz == PD - 1)
        p[idx] = (T)0;
}

// interleaved-by-4 halo: p[((cg*PD^3 + sp)*4 + c4], zero where sp is halo
__global__ __launch_bounds__(256)
void zero_halo_i4(unsigned short* __restrict__ p, int CG, int PD)
{
    long pd3 = (long)PD * PD * PD;
    long total = (long)CG * pd3 * 4;
    long idx = (long)blockIdx.x * blockDim.x + threadIdx.x;
    if (idx >= total) return;
    long sp = (idx >> 2) % pd3;
    int px = (int)(sp % PD); long t = sp / PD;
    int py = (int)(t % PD);
    int pz = (int)(t / PD);
    if (px == 0 || px == PD - 1 || py == 0 || py == PD - 1 || pz == 0 || pz == PD - 1)
        p[idx] = 0;
}

// ---------------------------------------------------------------------------
// Conv3d k4 s2 p1 as MFMA implicit GEMM, bf16 hi/lo pair inputs (enc1 only)
// ---------------------------------------------------------------------------
template <int CIN, int COUT, int DOUT, int PD, int PRX, int MTW, int OWT,
          int OWHALF, int KSPLIT, int OUTSPLIT>
__global__ __launch_bounds__(256)
void conv_s2_mfma(const unsigned short* __restrict__ xhi,
                  const unsigned short* __restrict__ xlo,
                  const short* __restrict__ Whi, const short* __restrict__ Wlo,
                  const float* __restrict__ bias,
                  unsigned short* __restrict__ yhi, unsigned short* __restrict__ ylo,
                  float* __restrict__ yf,
                  int OPD, int OPRX, int po, long sstride)
{
    constexpr int K = CIN * 64;
    constexpr int MWAVES = COUT / (16 * MTW);
    constexpr int RPB = 4 / MWAVES;
    constexpr int KN = (CIN * 2) / KSPLIT;

    int bx = blockIdx.x;
    const int ks = (KSPLIT > 1) ? (bx % KSPLIT) : 0;
    const int rowblk = (KSPLIT > 1) ? (bx / KSPLIT) : bx;
    const int lane = (int)threadIdx.x & 63, w = (int)threadIdx.x >> 6;
    const int mi = (MWAVES == 4) ? w : 0;
    const int ri = (MWAVES == 4) ? 0 : w;
    const int rowid = rowblk * RPB + ri;
    const int n16 = lane & 15, quad = lane >> 4;

    int b, od, oh, ow;
    if (OWHALF) {
        constexpr int NOH = DOUT / 2;
        const int ohb = rowid % NOH; int t = rowid / NOH;
        od = t % DOUT; b = t / DOUT;
        oh = ohb * 2 + (n16 >> 3);
        ow = n16 & 7;
    } else {
        const int owt = rowid % OWT; int t = rowid / OWT;
        oh = t % DOUT; t /= DOUT;
        od = t % DOUT; b = t / DOUT;
        ow = owt * 16 + n16;
    }

    const int co0 = mi * (MTW * 16);

    f32x4 acc[MTW];
    #pragma unroll
    for (int mt = 0; mt < MTW; ++mt)
        #pragma unroll
        for (int r = 0; r < 4; ++r) {
            int co = co0 + mt * 16 + quad * 4 + r;
            acc[mt][r] = (ks == 0) ? bias[co] : 0.0f;
        }

    const int sg0 = ks * KN;
    const long chs = (long)PD * PD * PRX;
    long off = ((long)(b * CIN + (sg0 >> 1)) * PD + (2 * od + (quad >> 1))) * PD * PRX
             + (long)(2 * oh + (quad & 1) * 2) * PRX + 2 * ow;
    const unsigned short* phi = xhi + off;
    const unsigned short* plo = xlo + off;
    const long incA = 2L * PD * PRX;
    const long incB = chs - 2L * PD * PRX;

    const short* a0h = Whi + (long)(co0 + n16) * K + sg0 * 32 + quad * 8;
    const short* a0l = Wlo + (long)(co0 + n16) * K + sg0 * 32 + quad * 8;

    #pragma unroll 2
    for (int s = 0; s < KN; ++s) {
        u16x4u h0 = *(const u16x4u*)phi;
        u16x4u h1 = *(const u16x4u*)(phi + PRX);
        u16x4u l0 = *(const u16x4u*)plo;
        u16x4u l1 = *(const u16x4u*)(plo + PRX);
        bf16x8 bhi = pack_b(h0, h1);
        bf16x8 blo = pack_b(l0, l1);
        #pragma unroll
        for (int mt = 0; mt < MTW; ++mt) {
            bf16x8 ah = *(const bf16x8*)(a0h + (long)mt * 16 * K + s * 32);
            bf16x8 al = *(const bf16x8*)(a0l + (long)mt * 16 * K + s * 32);
            acc[mt] = __builtin_amdgcn_mfma_f32_16x16x32_bf16(ah, bhi, acc[mt], 0, 0, 0);
            acc[mt] = __builtin_amdgcn_mfma_f32_16x16x32_bf16(ah, blo, acc[mt], 0, 0, 0);
            acc[mt] = __builtin_amdgcn_mfma_f32_16x16x32_bf16(al, bhi, acc[mt], 0, 0, 0);
        }
        long inc = (s & 1) ? incB : incA;
        phi += inc; plo += inc;
    }

    if (OUTSPLIT) {
        #pragma unroll
        for (int mt = 0; mt < MTW; ++mt)
            #pragma unroll
            for (int r = 0; r < 4; ++r) {
                int co = co0 + mt * 16 + quad * 4 + r;
                float v = fmaxf(acc[mt][r], 0.0f);
                unsigned short h, l;
                split_bf16(v, h, l);
                long o = (((long)(b * COUT + co) * OPD + od + po) * OPD + oh + po) * OPRX
                       + ow + po;
                yhi[o] = h; ylo[o] = l;
            }
    } else {
        #pragma unroll
        for (int mt = 0; mt < MTW; ++mt)
            #pragma unroll
            for (int r = 0; r < 4; ++r) {
                int co = co0 + mt * 16 + quad * 4 + r;
                long o = (long)ks * sstride
                       + (((long)(b * COUT + co) * OPD + od) * OPD + oh) * OPRX + ow;
                yf[o] = acc[mt][r];
            }
    }
}

// Fragment-direct variant (enc2/enc3): fragment-major Whi/Wlo, each wave
// loads its OWN disjoint (s,m) fragment blocks (coalesced 1KB dwordx4) --
// no LDS, no barriers. Bit-identical to the LDS path.
template <int CIN, int COUT, int DOUT, int PD, int PRX, int MTW, int OWT,
          int OWHALF, int KSPLIT, int OUTSPLIT>
__global__ __launch_bounds__(256)
void conv_s2_mfma_fd(const unsigned short* __restrict__ xhi,
                     const unsigned short* __restrict__ xlo,
                     const short* __restrict__ Whi, const short* __restrict__ Wlo,
                     const float* __restrict__ bias,
                     unsigned short* __restrict__ yhi, unsigned short* __restrict__ ylo,
                     float* __restrict__ yf,
                     int OPD, int OPRX, int po, long sstride)
{
    constexpr int MWAVES = COUT / (16 * MTW);
    constexpr int RPB = 4 / MWAVES;
    constexpr int KN = (CIN * 2) / KSPLIT;
    constexpr int MT = COUT >> 4;            // fragment-major m count
    constexpr int SSTEP = MT * 512;          // shorts per s-step in frag layout

    int bx = blockIdx.x;
    const int ks = (KSPLIT > 1) ? (bx % KSPLIT) : 0;
    const int rowblk = (KSPLIT > 1) ? (bx / KSPLIT) : bx;
    const int lane = (int)threadIdx.x & 63, w = (int)threadIdx.x >> 6;
    const int mi = (MWAVES == 4) ? w : 0;
    const int ri = (MWAVES == 4) ? 0 : w;
    const int rowid = rowblk * RPB + ri;
    const int n16 = lane & 15, quad = lane >> 4;

    int b, od, oh, ow;
    if (OWHALF) {
        constexpr int NOH = DOUT / 2;
        const int ohb = rowid % NOH; int t = rowid / NOH;
        od = t % DOUT; b = t / DOUT;
        oh = ohb * 2 + (n16 >> 3);
        ow = n16 & 7;
    } else {
        const int owt = rowid % OWT; int t = rowid / OWT;
        oh = t % DOUT; t /= DOUT;
        od = t % DOUT; b = t / DOUT;
        ow = owt * 16 + n16;
    }

    const int co0 = mi * (MTW * 16);

    f32x4 acc[MTW];
    #pragma unroll
    for (int mt = 0; mt < MTW; ++mt)
        #pragma unroll
        for (int r = 0; r < 4; ++r) {
            int co = co0 + mt * 16 + quad * 4 + r;
            acc[mt][r] = (ks == 0) ? bias[co] : 0.0f;
        }

    const int sg0 = ks * KN;
    const long chs = (long)PD * PD * PRX;
    long off = ((long)(b * CIN + (sg0 >> 1)) * PD + (2 * od + (quad >> 1))) * PD * PRX
             + (long)(2 * oh + (quad & 1) * 2) * PRX + 2 * ow;
    const unsigned short* phi = xhi + off;
    const unsigned short* plo = xlo + off;
    const long incA = 2L * PD * PRX;
    const long incB = chs - 2L * PD * PRX;

    // fragment-major: (s, m) block at ((s*MT + m)*64 + lane)*8
    const short* ph = Whi + (((long)sg0 * MT + mi * MTW) * 64 + lane) * 8;
    const short* pl = Wlo + (((long)sg0 * MT + mi * MTW) * 64 + lane) * 8;

    #pragma unroll 2
    for (int s = 0; s < KN; ++s) {
        u16x4u h0 = *(const u16x4u*)phi;
        u16x4u h1 = *(const u16x4u*)(phi + PRX);
        u16x4u l0 = *(const u16x4u*)plo;
        u16x4u l1 = *(const u16x4u*)(plo + PRX);
        bf16x8 bhi = pack_b(h0, h1);
        bf16x8 blo = pack_b(l0, l1);
        #pragma unroll
        for (int mt = 0; mt < MTW; ++mt) {
            bf16x8 ah = *(const bf16x8*)(ph + mt * 512);
            bf16x8 al = *(const bf16x8*)(pl + mt * 512);
            acc[mt] = __builtin_amdgcn_mfma_f32_16x16x32_bf16(ah, bhi, acc[mt], 0, 0, 0);
            acc[mt] = __builtin_amdgcn_mfma_f32_16x16x32_bf16(ah, blo, acc[mt], 0, 0, 0);
            acc[mt] = __builtin_amdgcn_mfma_f32_16x16x32_bf16(al, bhi, acc[mt], 0, 0, 0);
        }
        long inc = (s & 1) ? incB : incA;
        phi += inc; plo += inc;
        ph += SSTEP; pl += SSTEP;
    }

    if (OUTSPLIT) {
        #pragma unroll
        for (int mt = 0; mt < MTW; ++mt)
            #pragma unroll
            for (int r = 0; r < 4; ++r) {
                int co = co0 + mt * 16 + quad * 4 + r;
                float v = fmaxf(acc[mt][r], 0.0f);
                unsigned short h, l;
                split_bf16(v, h, l);
                long o = (((long)(b * COUT + co) * OPD + od + po) * OPD + oh + po) * OPRX
                       + ow + po;
                yhi[o] = h; ylo[o] = l;
            }
    } else {
        #pragma unroll
        for (int mt = 0; mt < MTW; ++mt)
            #pragma unroll
            for (int r = 0; r < 4; ++r) {
                int co = co0 + mt * 16 + quad * 4 + r;
                long o = (long)ks * sstride
                       + (((long)(b * COUT + co) * OPD + od) * OPD + oh) * OPRX + ow;
                yf[o] = acc[mt][r];
            }
    }
}

__global__ __launch_bounds__(256)
void combine4_relu(const float* __restrict__ p, float* __restrict__ y, long N, long ss)
{
    long idx = (long)blockIdx.x * blockDim.x + threadIdx.x;
    if (idx >= N) return;
    float v = p[idx] + p[idx + ss] + p[idx + 2 * ss] + p[idx + 3 * ss];
    y[idx] = fmaxf(v, 0.0f);
}

// ---------------- 1x1 conv (fp32 exact) ----------------
__global__ __launch_bounds__(128)
void conv1x1_b(const float* __restrict__ x, const float* __restrict__ w,
               const float* __restrict__ bias, float* __restrict__ y)
{
    const int co = blockIdx.x & 255, b = blockIdx.x >> 8;
    const int s4 = (int)threadIdx.x * 4;
    const float* xb = x + (long)b * 256 * 512 + s4;
    const float* wr = w + (long)co * 256;      // uniform -> s_load
    float bv = bias[co];
    float4 acc = {bv, bv, bv, bv};
    for (int ci = 0; ci < 256; ++ci) {
        float wv = wr[ci];
        float4 xv = *(const float4*)(xb + (long)ci * 512);
        acc.x = fmaf(xv.x, wv, acc.x); acc.y = fmaf(xv.y, wv, acc.y);
        acc.z = fmaf(xv.z, wv, acc.z); acc.w = fmaf(xv.w, wv, acc.w);
    }
    *(float4*)(y + (long)(b * 256 + co) * 512 + s4) = acc;
}

// ---------------- VQ (fp32 exact) ----------------
__global__ void codenorm_kernel(const float* __restrict__ cb, float* __restrict__ norms)
{
    int k = blockIdx.x;
    int lane = threadIdx.x;
    float s = 0.0f;
    const float* row = cb + (long)k * 256;
    for (int d = lane; d < 256; d += 64) { float v = row[d]; s = fmaf(v, v, s); }
    for (int off = 32; off > 0; off >>= 1) s += __shfl_down(s, off);
    if (lane == 0) norms[k] = s;
}

// cbT[d*1024 + k] = cb[k*256 + d]  (fp32 copy -> values unchanged)
__global__ __launch_bounds__(256)
void transpose_cb(const float* __restrict__ cb, float* __restrict__ cbT)
{
    int idx = blockIdx.x * 256 + (int)threadIdx.x;    // 0..262143
    int d = idx & 255, k = idx >> 8;
    cbT[(long)d * 1024 + k] = cb[(long)k * 256 + d];
}

// R24: 4 rows/block (grid 256), coalesced cbT float4 loads (codes 4t..4t+3),
// rows staged in LDS. Bit-identical to the original per-row kernel.
__global__ __launch_bounds__(256)
void vq_kernel4(const float* __restrict__ lat, const float* __restrict__ cb,
                const float* __restrict__ cbT, const float* __restrict__ norms,
                unsigned short* __restrict__ q, float* __restrict__ idx_out)
{
    __shared__ __align__(16) float rows[4][256];
    __shared__ float s_best[4][256];
    __shared__ int   s_bidx[4][256];
    const int r0 = blockIdx.x * 4;
    const int t = (int)threadIdx.x;

    #pragma unroll
    for (int j = 0; j < 4; ++j)
        rows[j][t] = lat[(long)(r0 + j) * 256 + t];
    __syncthreads();

    // latn per row -- identical float4 fmaf chain to the original
    float latn[4];
    #pragma unroll
    for (int j = 0; j < 4; ++j) {
        const float4* rowv = (const float4*)rows[j];
        float a = 0.0f;
        #pragma unroll 4
        for (int d = 0; d < 64; ++d) {
            float4 rv = rowv[d];
            a = fmaf(rv.x, rv.x, a); a = fmaf(rv.y, rv.y, a);
            a = fmaf(rv.z, rv.z, a); a = fmaf(rv.w, rv.w, a);
        }
        latn[j] = a;
    }

    // codes 4t..4t+3; dot[j][c] accumulates d = 0..255 sequentially (same
    // chain as the original scalar loop)
    float dot[4][4] = {};
    const float* ct = cbT + t * 4;
    #pragma unroll 4
    for (int d = 0; d < 256; ++d) {
        float4 c4 = *(const float4*)(ct + (long)d * 1024);
        #pragma unroll
        for (int j = 0; j < 4; ++j) {
            float rv = rows[j][d];
            dot[j][0] = fmaf(rv, c4.x, dot[j][0]);
            dot[j][1] = fmaf(rv, c4.y, dot[j][1]);
            dot[j][2] = fmaf(rv, c4.z, dot[j][2]);
            dot[j][3] = fmaf(rv, c4.w, dot[j][3]);
        }
    }

    float4 nv = *(const float4*)(norms + t * 4);
    float nr[4] = {nv.x, nv.y, nv.z, nv.w};

    #pragma unroll
    for (int j = 0; j < 4; ++j) {
        float best = FLT_MAX;
        int bidx = 0x7fffffff;
        #pragma unroll
        for (int c = 0; c < 4; ++c) {
            float sc = latn[j] - 2.0f * dot[j][c] + nr[c];
            int k = t * 4 + c;
            if (sc < best || (sc == best && k < bidx)) { best = sc; bidx = k; }
        }
        s_best[j][t] = best; s_bidx[j][t] = bidx;
    }
    __syncthreads();
    for (int off = 128; off > 0; off >>= 1) {
        if (t < off) {
            #pragma unroll
            for (int j = 0; j < 4; ++j) {
                float o = s_best[j][t + off]; int oi = s_bidx[j][t + off];
                if (o < s_best[j][t] || (o == s_best[j][t] && oi < s_bidx[j][t])) {
                    s_best[j][t] = o; s_bidx[j][t] = oi;
                }
            }
        }
        __syncthreads();
    }

    #pragma unroll
    for (int j = 0; j < 4; ++j) {
        const int bk = s_bidx[j][0];
        const int r = r0 + j;
        const int b = r >> 9, n = r & 511;
        const int zz = n >> 6, yy = (n >> 3) & 7, xx = n & 7;
        q[(long)(b * 256 + t) * 1000 + ((long)(zz + 1) * 10 + (yy + 1)) * 10 + (xx + 1)]
            = f32_to_bf16(cb[(long)bk * 256 + t]);
    }
    if (t == 0) {
        #pragma unroll
        for (int j = 0; j < 4; ++j)
            idx_out[r0 + j] = (float)s_bidx[j][0];
    }
}

// ---------------- decoder: MFMA implicit-GEMM ConvTranspose ----------------
// xflip=0: B slot a <-> x offset (1-ax), kw=(1-px)+2*ax (old cube kernel).
// xflip=1: B slot a <-> x offset ax,     kw=(1-px)+2*(1-ax) (dword-pair kernel).
__global__ __launch_bounds__(256)
void prep_convt_w(const float* __restrict__ w, short* __restrict__ Ap,
                  int Cin, int Cout, int xflip)
{
    const int K = Cin * 8;
    long total = 8L * Cout * K;
    long idx = (long)blockIdx.x * blockDim.x + threadIdx.x;
    if (idx >= total) return;
    int k = (int)(idx % K);
    int co = (int)((idx / K) % Cout);
    int p = (int)(idx / ((long)K * Cout));
    int ci = k >> 3, a = k & 7;
    int az = (a >> 2) & 1, ay = (a >> 1) & 1, ax = a & 1;
    int pz = p >> 2, py = (p >> 1) & 1, px = p & 1;
    int axw = xflip ? (1 - ax) : ax;
    int kd = (1 - pz) + 2 * az, kh = (1 - py) + 2 * ay, kw = (1 - px) + 2 * axw;
    float v = w[((long)ci * Cout + co) * 64 + kd * 16 + kh * 4 + kw];
    Ap[idx] = (short)f32_to_bf16(v);
}

// Fragment-major layout for the LDS-staged v2 kernel:
//   ApN[((p*MG + mg)*nsteps + s)*2048 + cb*512 + l*8 + kk]
__global__ __launch_bounds__(256)
void prep_convt_w_frag(const float* __restrict__ w, short* __restrict__ Ap,
                       int Cin, int Cout, int xflip)
{
    const int MG = Cout >> 6;
    const int nsteps = Cin >> 2;             // (Cin*8)/32
    long total = 8L * MG * nsteps * 2048;
    long idx = (long)blockIdx.x * blockDim.x + threadIdx.x;
    if (idx >= total) return;
    int kk = (int)(idx & 7); long r = idx >> 3;
    int l  = (int)(r & 63);  r >>= 6;
    int cb = (int)(r & 3);   r >>= 2;
    int s  = (int)(r % nsteps); r /= nsteps;
    int mg = (int)(r % MG);
    int p  = (int)(r / MG);

    int n16 = l & 15, quad = l >> 4;
    int korig = s * 32 + quad * 8 + kk;
    int co = mg * 64 + cb * 16 + n16;
    int ci = korig >> 3, a = korig & 7;
    int az = (a >> 2) & 1, ay = (a >> 1) & 1, ax = a & 1;
    int pz = p >> 2, py = (p >> 1) & 1, px = p & 1;
    int axw = xflip ? (1 - ax) : ax;
    int kd = (1 - pz) + 2 * az, kh = (1 - py) + 2 * ay, kw = (1 - px) + 2 * axw;
    float v = w[((long)ci * Cout + co) * 64 + kd * 16 + kh * 4 + kw];
    Ap[idx] = (short)f32_to_bf16(v);
}

// Old cube-N layout (kept for dec1, DIN=8): round-0 body.
template <int CIN, int COUT, int DIN, int OPAD, typename OutT>
__global__ __launch_bounds__(256)
void convt_mfma(const unsigned short* __restrict__ Xp, const short* __restrict__ Ap,
                const float* __restrict__ bias, OutT* __restrict__ Y)
{
    constexpr int PD = DIN + 2;
    constexpr int PD3 = PD * PD * PD;
    constexpr int T = DIN >> 2;
    constexpr int NT = T * T * T;
    constexpr int SLAB = NT / 8;
    constexpr int OPD = 2 * DIN + 2 * OPAD;
    constexpr int K = CIN * 8;
    constexpr int MG = COUT >> 6;
    constexpr int nsteps = K >> 5;

    int bx = blockIdx.x;
    const int xcd = bx & 7;
    int local = bx >> 3;
    const int px = local & 1; local >>= 1;
    const int mg = local % MG; local /= MG;
    const int ntin = local % SLAB;
    const int pzy = local / SLAB;            // 0..3
    const int pz = pzy >> 1, py = pzy & 1;
    const int p = pz * 4 + py * 2 + px;
    const int nt = xcd * SLAB + ntin;

    const int lane = threadIdx.x & 63, wave = threadIdx.x >> 6;
    const int n16 = lane & 15, quad = lane >> 4;

    const int tx = nt % T, ty = (nt / T) % T, tz = nt / (T * T);
    const int mz = tz * 4 + wave, my = ty * 4 + (n16 >> 2), mx = tx * 4 + (n16 & 3);
    const int sp = ((mz + pz) * PD + (my + py)) * PD + (mx + px);

    const unsigned short* xq = Xp + (long)quad * PD3 + sp;

    const int cobase = mg * 64;
    const short* ap0 = Ap + ((long)p * COUT + cobase + n16) * K + quad * 8;

    f32x4 acc[4];
    #pragma unroll
    for (int cb = 0; cb < 4; ++cb) {
        const float* bp = bias + cobase + cb * 16 + quad * 4;
        acc[cb][0] = bp[0]; acc[cb][1] = bp[1]; acc[cb][2] = bp[2]; acc[cb][3] = bp[3];
    }

    #pragma unroll 4
    for (int s = 0; s < nsteps; ++s) {
        const unsigned short* xs = xq + (long)s * 4 * PD3;
        bf16x8 bf;
        bf[0] = (short)xs[(PD + 1) * PD + 1];
        bf[1] = (short)xs[(PD + 1) * PD];
        bf[2] = (short)xs[PD * PD + 1];
        bf[3] = (short)xs[PD * PD];
        bf[4] = (short)xs[PD + 1];
        bf[5] = (short)xs[PD];
        bf[6] = (short)xs[1];
        bf[7] = (short)xs[0];
        #pragma unroll
        for (int cb = 0; cb < 4; ++cb) {
            bf16x8 af = *(const bf16x8*)(ap0 + (long)cb * 16 * K + s * 32);
            acc[cb] = __builtin_amdgcn_mfma_f32_16x16x32_bf16(af, bf, acc[cb], 0, 0, 0);
        }
    }

    const int opz = 2 * mz + pz + OPAD, opy = 2 * my + py + OPAD, opx = 2 * mx + px + OPAD;
    const long spo = ((long)opz * OPD + opy) * OPD + opx;
    #pragma unroll
    for (int cb = 0; cb < 4; ++cb) {
        #pragma unroll
        for (int r = 0; r < 4; ++r) {
            int co = cobase + cb * 16 + quad * 4 + r;
            float v = fmaxf(acc[cb][r], 0.0f);
            store_act(Y + (long)co * OPD * OPD * OPD + spo, v);
        }
    }
}

// Dword-pair B-gather (dec2/dec3), R29 2-step phases + R31 interleave:
// IIN: X input is channel-interleaved [cg][spatial][4]; one dwordx4/lane
//      covers both x-taps x 4 channels; extraction = shorts[quad],[quad+4].
// IOUT: output written channel-interleaved; each (t,cb) column -> one 8B
//      store of 4 RNE-bf16 (co&3 == r).
// Per-acc MFMA order = old sequential s; identical tap values => bit-identical.
template <int CIN, int COUT, int DIN, int OPAD, int MXP, int MYP, int IIN, int IOUT,
          typename OutT>
__global__ __launch_bounds__(256)
void convt_mfma_v2(const unsigned short* __restrict__ Xp, const short* __restrict__ Ap,
                   const float* __restrict__ bias, OutT* __restrict__ Y)
{
    constexpr int PD = DIN + 2;
    constexpr int PD3 = PD * PD * PD;
    constexpr int OPD = 2 * DIN + 2 * OPAD;
    constexpr int K = CIN * 8;
    constexpr int MG = COUT >> 6;
    constexpr int nsteps = K >> 5;
    static_assert((nsteps & 1) == 0 && nsteps >= 4, "phase merge needs even nsteps");
    constexpr int NPH = nsteps / 2;
    constexpr int MXT = DIN / (16 * MXP);
    constexpr int MYT = DIN / (4 * MYP);
    constexpr int MZS = DIN / 8;             // mz per XCD slab
    constexpr int TPE = MXP * MYP;           // tiles per wave (one of MXP/MYP is 1)

    int bx = blockIdx.x;
    const int xcd = bx & 7;
    int local = bx >> 3;
    const int px = local & 1; local >>= 1;
    const int py = local & 1; local >>= 1;
    const int mg = local % MG; local /= MG;
    const int mxt = local % MXT; local /= MXT;
    const int myt = local % MYT; local /= MYT;
    const int pz = local & 1; local >>= 1;
    const int mzin = local;                  // 0..MZS-1
    const int mz = xcd * MZS + mzin;
    const int p = pz * 4 + py * 2 + px;

    const int lane = threadIdx.x & 63, wave = threadIdx.x >> 6;
    const int n16 = lane & 15, quad = lane >> 4;

    const int mx0 = mxt * (16 * MXP) + n16;
    const int my0 = myt * (4 * MYP) + wave * MYP;
    const int baseX = mx0 & ~1;
    const int sh = 16 * ((n16 & 1) + px);    // 0, 16, or 32 (IIN=0 path)
    const int shq = 16 * quad;               // IIN=1 extraction shift

    // IIN=0: per-quad channel planes, even-x base. IIN=1: quad-independent
    // spatial address with full x (= mx0 + px).
    const long spLin = ((long)(mz + pz) * PD + (my0 + py)) * PD + baseX;
    const long spInt = ((long)(mz + pz) * PD + (my0 + py)) * PD + mx0 + px;
    const unsigned short* xq = IIN ? Xp : (Xp + (long)quad * PD3 + spLin);

    // fragment-major weight tiles: 2048 shorts (4KB) per (p,mg,s)
    const short* ApT = Ap + (((long)p * MG + mg) * nsteps) * 2048;

    __shared__ short Abuf[2][2][2048];       // 16KB: dbuf x 2-steps x 4KB

    f32x4 acc[TPE][4];
    #pragma unroll
    for (int t = 0; t < TPE; ++t)
        #pragma unroll
        for (int cb = 0; cb < 4; ++cb) {
            const float* bp = bias + (mg * 64) + cb * 16 + quad * 4;
            acc[t][cb][0] = bp[0]; acc[t][cb][1] = bp[1];
            acc[t][cb][2] = bp[2]; acc[t][cb][3] = bp[3];
        }

    constexpr int rowoff[4] = { (PD + 1) * PD, PD * PD, PD, 0 };
    union Frag { unsigned u[4]; bf16x8 b; };

    const int chunkoff = wave * 512 + lane * 8;   // this thread's 16B of a 4KB tile

    // prologue: stage steps 0 and 1
    {
        *(bf16x8*)(&Abuf[0][0][chunkoff]) = *(const bf16x8*)(ApT + chunkoff);
        *(bf16x8*)(&Abuf[0][1][chunkoff]) = *(const bf16x8*)(ApT + 2048 + chunkoff);
    }
    __syncthreads();

    #pragma unroll 1
    for (int ph = 0; ph < NPH; ++ph) {
        const int cur = ph & 1;
        const bool more = (ph + 1 < NPH);
        bf16x8 an0, an1;
        if (more) {
            an0 = *(const bf16x8*)(ApT + (long)(2 * ph + 2) * 2048 + chunkoff);
            an1 = *(const bf16x8*)(ApT + (long)(2 * ph + 3) * 2048 + chunkoff);
        }

        // X loads for both steps (raw staging)
        unsigned long long xr[2][TPE][4];        // IIN=0
        u16x8a4 raw16[2][TPE][4];                // IIN=1
        #pragma unroll
        for (int u = 0; u < 2; ++u) {
            const int s = 2 * ph + u;
            #pragma unroll
            for (int t = 0; t < TPE; ++t) {
                const int toff = (MXP > 1) ? t * 16 : t * PD;
                #pragma unroll
                for (int j = 0; j < 4; ++j) {
                    if constexpr (IIN) {
                        raw16[u][t][j] = *(const u16x8a4*)(
                            Xp + ((long)s * PD3 + spInt + toff + rowoff[j]) * 4);
                    } else {
                        const unsigned short* xs = xq + (long)s * 4 * PD3;
                        union { u16x4u v; unsigned long long u64; } ld;
                        ld.v = *(const u16x4u*)(xs + toff + rowoff[j]);
                        xr[u][t][j] = ld.u64;
                    }
                }
            }
        }

        // A fragments from LDS for both steps
        bf16x8 af[2][4];
        #pragma unroll
        for (int u = 0; u < 2; ++u)
            #pragma unroll
            for (int cb = 0; cb < 4; ++cb)
                af[u][cb] = *(const bf16x8*)(&Abuf[cur][u][cb * 512 + lane * 8]);

        // MFMA: step 2ph then 2ph+1 (old sequential order)
        #pragma unroll
        for (int u = 0; u < 2; ++u) {
            #pragma unroll
            for (int t = 0; t < TPE; ++t) {
                Frag fr;
                #pragma unroll
                for (int j = 0; j < 4; ++j) {
                    if constexpr (IIN) {
                        union { u16x8a4 v; unsigned long long q[2]; } c;
                        c.v = raw16[u][t][j];
                        unsigned lo = (unsigned)((c.q[0] >> shq) & 0xffffULL);
                        unsigned hi = (unsigned)((c.q[1] >> shq) & 0xffffULL);
                        fr.u[j] = lo | (hi << 16);
                    } else {
                        fr.u[j] = (unsigned)(xr[u][t][j] >> sh);
                    }
                }
                #pragma unroll
                for (int cb = 0; cb < 4; ++cb)
                    acc[t][cb] = __builtin_amdgcn_mfma_f32_16x16x32_bf16(af[u][cb], fr.b,
                                                                         acc[t][cb], 0, 0, 0);
            }
        }

        if (more) {
            *(bf16x8*)(&Abuf[cur ^ 1][0][chunkoff]) = an0;
            *(bf16x8*)(&Abuf[cur ^ 1][1][chunkoff]) = an1;
        }
        __syncthreads();
    }

    const int opz = 2 * mz + pz + OPAD;
    #pragma unroll
    for (int t = 0; t < TPE; ++t) {
        const int opx = 2 * (mx0 + ((MXP > 1) ? t * 16 : 0)) + px + OPAD;
        const int opy = 2 * (my0 + ((MYP > 1) ? t : 0)) + py + OPAD;
        const long spo = ((long)opz * OPD + opy) * OPD + opx;
        #pragma unroll
        for (int cb = 0; cb < 4; ++cb) {
            if constexpr (IOUT) {
                // co = mg*64 + cb*16 + quad*4 + r -> cg = mg*16+cb*4+quad, c4 = r
                const int cg = mg * 16 + cb * 4 + quad;
                u16x4u st;
                #pragma unroll
                for (int r = 0; r < 4; ++r)
                    st[r] = f32_to_bf16(fmaxf(acc[t][cb][r], 0.0f));
                *(u16x4u*)((unsigned short*)Y + ((long)cg * OPD * OPD * OPD + spo) * 4) = st;
            } else {
                #pragma unroll
                for (int r = 0; r < 4; ++r) {
                    int co = (mg * 64) + cb * 16 + quad * 4 + r;
                    float v = fmaxf(acc[t][cb][r], 0.0f);
                    store_act(Y + (long)co * OPD * OPD * OPD + spo, v);
                }
            }
        }
    }
}

// ---------------- dec4 as MFMA GEMM, R30: bf16 d3 input ----------------
// Fragment-major: Aw[(s*64 + lane)*8 + kk] (unchanged from R23).
__global__ __launch_bounds__(256)
void prep_dec4A_frag(const float* __restrict__ w, short* __restrict__ Aw)
{
    int idx = blockIdx.x * 256 + (int)threadIdx.x;    // 0..65535
    int kk = idx & 7;
    int l  = (idx >> 3) & 63;
    int s  = idx >> 9;                                // 0..127
    int n16 = l & 15, quad = l >> 4;
    int k = s * 32 + quad * 8 + kk;
    float v = (n16 < 3) ? w[n16 * 4096 + k] : 0.0f;
    Aw[idx] = (short)f32_to_bf16(v);
}

// R30: d3 truncated-bf16 (ushort); Xs ushort[2][28][80]; RS=80 read windows
// {0,16,24,8} (free); strided staging (64 consecutive shorts/wave-pass).
// Fragment words rebuilt via 64-bit shifts: bit-identical.
__global__ __launch_bounds__(256)
void conv_dec4_mfma(const unsigned short* __restrict__ d3h, const short* __restrict__ Aw,
                    const float* __restrict__ bias, float* __restrict__ y)
{
    constexpr int D = 64, Dout = 61;
    constexpr int RS = 80;                 // row stride (shorts)
    int bx = blockIdx.x;
    const int slab = bx & 7;
    const int i = bx >> 3;                 // 0..127
    const int od = slab * 8 + (i >> 4);
    const int oh0 = (i & 15) * 4;          // covers oh0..oh0+3 (guard < 61)
    if (od >= Dout) return;                // uniform per block -> barriers safe
    const int tid = (int)threadIdx.x;
    const int lane = tid & 63, wave = tid >> 6;
    const int n16 = lane & 15, quad = lane >> 4;
    const int ow = wave * 16 + n16;

    __shared__ unsigned short Xs[2][28][RS];
    unsigned short* xsb = &Xs[0][0][0];
    constexpr int BUFW = 28 * RS;          // shorts per buffer

    f32x4 acc[4];
    #pragma unroll
    for (int j = 0; j < 4; ++j)
        #pragma unroll
        for (int r = 0; r < 4; ++r) {
            int co = quad * 4 + r;
            acc[j][r] = (co < 3) ? bias[co] : 0.0f;
        }

    const int kd0 = quad >> 1;
    const int kh0 = (quad & 1) * 2;
    const int sha = 16 * (ow & 1);
    const int owb = ow & ~1;

    const bool sact = (tid < 224);
    int goff[8];                           // global short offset (ci-invariant)
    int loff[8];                           // LDS short offset within a buffer
    #pragma unroll
    for (int j = 0; j < 8; ++j) {
        const int g = tid + 224 * j;
        const int row = g >> 6, xx = g & 63;
        const int szi = row / 7, syi = row % 7;
        goff[j] = ((od + szi) * D + min(oh0 + syi, D - 1)) * D + xx;
        loff[j] = row * RS + xx;
    }
    auto choff = [](int S) { return (long)S * D * D * D; };

    if (sact) {
        #pragma unroll
        for (int j = 0; j < 8; ++j)
            xsb[loff[j]] = d3h[goff[j]];
    }
    __syncthreads();

    #pragma unroll 1
    for (int S = 0; S < 64; ++S) {
        const int cur = S & 1;
        const bool more = (S + 1 < 64);
        unsigned short nv[8];
        if (more && sact) {
            const unsigned short* src = d3h + choff(S + 1);
            #pragma unroll
            for (int j = 0; j < 8; ++j)
                nv[j] = src[goff[j]];
        }

        #pragma unroll
        for (int h = 0; h < 2; ++h) {
            bf16x8 af = *(const bf16x8*)(Aw + ((long)(2 * S + h) * 64 + lane) * 8);
            unsigned p0[5], p1[5];
            #pragma unroll
            for (int r = 0; r < 5; ++r) {
                const int row = 14 * h + kd0 * 7 + kh0 + r;
                union { u16x8a4 v; unsigned long long q[2]; } ld;
                ld.v = *(const u16x8a4*)(xsb + cur * BUFW + row * RS + owb);
                p0[r] = (unsigned)(ld.q[0] >> sha);
                p1[r] = (unsigned)(((ld.q[0] >> 32) | (ld.q[1] << 32)) >> sha);
            }
            #pragma unroll
            for (int j = 0; j < 4; ++j) {
                union { unsigned u[4]; bf16x8 b; } fr;
                fr.u[0] = p0[j];     fr.u[1] = p1[j];
                fr.u[2] = p0[j + 1]; fr.u[3] = p1[j + 1];
                acc[j] = __builtin_amdgcn_mfma_f32_16x16x32_bf16(af, fr.b, acc[j], 0, 0, 0);
            }
        }

        if (more && sact) {
            unsigned short* dst = xsb + (cur ^ 1) * BUFW;
            #pragma unroll
            for (int j = 0; j < 8; ++j)
                dst[loff[j]] = nv[j];
        }
        __syncthreads();
    }

    if (ow < Dout && quad == 0) {
        #pragma unroll
        for (int j = 0; j < 4; ++j) {
            const int oh = oh0 + j;
            if (oh >= Dout) continue;
            #pragma unroll
            for (int r = 0; r < 3; ++r)
                y[((long)(r * Dout + od) * Dout + oh) * Dout + ow] = tanhf(acc[j][r]);
        }
    }
}

extern "C" void kernel_launch(void* const* d_in, const int* in_sizes, int n_in,
                              void* d_out, int out_size, void* d_ws, size_t ws_size,
                              hipStream_t stream)
{
    const float* x        = (const float*)d_in[0];
    const float* enc_w1   = (const float*)d_in[1];
    const float* enc_b1   = (const float*)d_in[2];
    const float* enc_w2   = (const float*)d_in[3];
    const float* enc_b2   = (const float*)d_in[4];
    const float* enc_w3   = (const float*)d_in[5];
    const float* enc_b3   = (const float*)d_in[6];
    const float* enc_w4   = (const float*)d_in[7];
    const float* enc_b4   = (const float*)d_in[8];
    const float* codebook = (const float*)d_in[9];
    const float* dec_w1   = (const float*)d_in[10];
    const float* dec_b1   = (const float*)d_in[11];
    const float* dec_w2   = (const float*)d_in[12];
    const float* dec_b2   = (const float*)d_in[13];
    const float* dec_w3   = (const float*)d_in[14];
    const float* dec_b3   = (const float*)d_in[15];
    const float* dec_w4   = (const float*)d_in[16];
    const float* dec_b4   = (const float*)d_in[17];

    float* out = (float*)d_out;
    float* idx_out = out + 2L * 3 * 61 * 61 * 61;

    // ---- workspace (byte offsets) ----
    char* wsb = (char*)d_ws;
    float*          cn   = (float*)wsb;                        //      4,096
    unsigned short* qp   = (unsigned short*)(wsb + 4096);      //  1,024,000
    short*          Ap1  = (short*)(wsb + 1028096);            //  8,388,608
    short*          Ap2  = (short*)(wsb + 9416704);            //  4,194,304
    short*          Ap3  = (short*)(wsb + 13611008);           //  1,048,576
    short*          Aw4  = (short*)(wsb + 14659584);           //    131,072
    short*          W1hi = (short*)(wsb + 14790656);           //     24,576
    short*          W1lo = (short*)(wsb + 14815232);           //     24,576
    short*          W2hi = (short*)(wsb + 14839808);           //  1,048,576
    short*          W2lo = (short*)(wsb + 15888384);           //  1,048,576
    short*          W3hi = (short*)(wsb + 16936960);           //  4,194,304
    short*          W3lo = (short*)(wsb + 21131264);           //  4,194,304
    char* arena = wsb + 25325568;
    // encoder phase:
    unsigned short* xphi = (unsigned short*)arena;                    // (2,3,66,66,68)
    unsigned short* xplo = (unsigned short*)(arena + 3554496);
    unsigned short* h1hi = (unsigned short*)(arena + 7108992);        // (2,64,34,34,36)
    unsigned short* h1lo = (unsigned short*)(arena + 17762688);
    unsigned short* h2hi = (unsigned short*)(arena + 28416384);       // (2,128,18,18,20)
    unsigned short* h2lo = (unsigned short*)(arena + 31734144);
    float*          pp3  = (float*)(arena + 35051904);                // 4x(2,256,8^3)
    float*          h3   = (float*)(arena + 39246208);                // (2,256,512)
    float*          lat  = (float*)(arena + 40294784);                // (2,256,512)
    // decoder phase (after VQ; overlaps encoder buffers):
    unsigned short* d1 = (unsigned short*)arena;                      // (256,18^3) bf16
    unsigned short* d2 = (unsigned short*)(arena + 2985984);          // (32,34^3,4) bf16 ilv
    bf16t*          d3 = (bf16t*)(arena + 13047808);                  // (64,64^3) bf16-trunc
    // arena peak < 80.2 MB -> ws used 105.5 MB; cbT appended below:
    float*          cbT = (float*)(wsb + 105482240);                  // 1,048,576
    // total 106.5 MB (< 112.2 MB proven in R0)

    dim3 blk(256);
    auto nblk = [](long n) { return dim3((unsigned)((n + 255) / 256)); };

    // ---- weight prep ----
    prep_convt_w<<<nblk(8L * 256 * 2048), blk, 0, stream>>>(dec_w1, Ap1, 256, 256, 0);
    prep_convt_w_frag<<<nblk(8L * 128 * 2048), blk, 0, stream>>>(dec_w2, Ap2, 256, 128, 1);
    prep_convt_w_frag<<<nblk(8L * 64 * 1024), blk, 0, stream>>>(dec_w3, Ap3, 128, 64, 1);
    prep_dec4A_frag<<<dim3(256), blk, 0, stream>>>(dec_w4, Aw4);
    prep_split_w<<<nblk(12288), blk, 0, stream>>>(enc_w1, W1hi, W1lo, 12288);
    prep_split_w_frag<<<nblk(524288), blk, 0, stream>>>(enc_w2, W2hi, W2lo, 64, 128);
    prep_split_w_frag<<<nblk(2097152), blk, 0, stream>>>(enc_w3, W3hi, W3lo, 128, 256);
    transpose_cb<<<dim3(1024), blk, 0, stream>>>(codebook, cbT);

    // ---- encoder (MFMA, bf16-pair) ----
    pad_input_split<<<nblk(6L * 66 * 66 * 68), blk, 0, stream>>>(x, xphi, xplo);
    zero_halo_ps<<<nblk(128L * 34 * 34 * 36), blk, 0, stream>>>(h1hi, 128, 34, 36);
    zero_halo_ps<<<nblk(128L * 34 * 34 * 36), blk, 0, stream>>>(h1lo, 128, 34, 36);
    conv_s2_mfma<3, 64, 32, 66, 68, 4, 2, 0, 1, 1><<<dim3(1024), blk, 0, stream>>>(
        xphi, xplo, W1hi, W1lo, enc_b1, h1hi, h1lo, nullptr, 34, 36, 1, 0);
    zero_halo_ps<<<nblk(256L * 18 * 18 * 20), blk, 0, stream>>>(h2hi, 256, 18, 20);
    zero_halo_ps<<<nblk(256L * 18 * 18 * 20), blk, 0, stream>>>(h2lo, 256, 18, 20);
    conv_s2_mfma_fd<64, 128, 16, 34, 36, 2, 1, 0, 1, 1><<<dim3(512), blk, 0, stream>>>(
        h1hi, h1lo, W2hi, W2lo, enc_b2, h2hi, h2lo, nullptr, 18, 20, 1, 0);
    conv_s2_mfma_fd<128, 256, 8, 18, 20, 4, 1, 1, 4, 0><<<dim3(256), blk, 0, stream>>>(
        h2hi, h2lo, W3hi, W3lo, enc_b3, nullptr, nullptr, pp3, 8, 8, 0, 262144);
    combine4_relu<<<nblk(262144), blk, 0, stream>>>(pp3, h3, 262144, 262144);
    conv1x1_b<<<dim3(512), dim3(128), 0, stream>>>(h3, enc_w4, enc_b4, lat);

    // ---- VQ (fp32 exact) ----
    codenorm_kernel<<<dim3(1024), dim3(64), 0, stream>>>(codebook, cn);
    zero_halo_t<unsigned short><<<nblk(512L * 10 * 10 * 10), blk, 0, stream>>>(qp, 512, 10);
    vq_kernel4<<<dim3(256), blk, 0, stream>>>(lat, codebook, cbT, cn, qp, idx_out);

    // ---- decoder halos ----
    zero_halo_t<unsigned short><<<nblk(256L * 18 * 18 * 18), blk, 0, stream>>>(d1, 256, 18);
    zero_halo_i4<<<nblk(128L * 34 * 34 * 34), blk, 0, stream>>>(d2, 32, 34);

    // ---- decoder (MFMA) per batch ----
    for (int b = 0; b < 2; ++b) {
        const unsigned short* qb = qp + (long)b * 256 * 1000;
        float* outb = out + (long)b * 3 * 226981;
        // dec1 (DIN=8, old layout): grid = 8*2*4*1*4 = 256
        convt_mfma<256, 256, 8, 1, unsigned short><<<dim3(256), blk, 0, stream>>>(
            qb, Ap1, dec_b1, d1);
        // dec2 (v2, MXP=1 MYP=2, IOUT=1 interleaved): grid 512
        convt_mfma_v2<256, 128, 16, 1, 1, 2, 0, 1, unsigned short>
            <<<dim3(512), blk, 0, stream>>>(d1, Ap2, dec_b2, d2);
        // dec3 (v2, MXP=2 MYP=1, IIN=1 interleaved): grid 2048, bf16t out
        convt_mfma_v2<128, 64, 32, 0, 2, 1, 1, 0, bf16t>
            <<<dim3(2048), blk, 0, stream>>>(d2, Ap3, dec_b3, d3);
        conv_dec4_mfma<<<dim3(8 * 8 * 16), blk, 0, stream>>>(
            (const unsigned short*)d3, Aw4, dec_b4, outb);
    }
}

// Round 15
// 888.668 us; speedup vs baseline: 1.0057x; 1.0057x over previous
//
#include <hip/hip_runtime.h>
#include <cfloat>
#include <cmath>

// ---------------------------------------------------------------------------
// Round 32 = revert to R30 (proven best, 883us).
// R31 post-mortem: channel-interleave REGRESSED (dec3 87.4 -> 91.3us,
// VALUBusy 15 -> 24 from extraction shifts; total 883 -> 894). dec3 has now
// resisted four structural attacks (R29 barrier-merge null, R30 write-halve
// byte-confirmed/dur-flat, R31 interleave regression) -- ~87us plateau with
// all counters <40%. Remaining hypothesis is L2 request bandwidth from
// per-lane 8B loads; the fix (cooperative X LDS staging) costs a 5-block/CU
// occupancy cliff and high gather-semantics risk, not worth it after R31's
// lesson. This round restores the best-known configuration exactly:
// R20-R28 wins + R29 2-step phases + R30 bf16-truncated d3.
// ---------------------------------------------------------------------------

using f32x4  = __attribute__((ext_vector_type(4))) float;
using bf16x8 = __attribute__((ext_vector_type(8))) short;
typedef float f32x4u __attribute__((ext_vector_type(4), aligned(4)));
typedef unsigned short u16x4u __attribute__((ext_vector_type(4), aligned(4)));
typedef unsigned short u16x8a4 __attribute__((ext_vector_type(8), aligned(4)));

__device__ __forceinline__ unsigned short f32_to_bf16(float f) {
    unsigned int u = __float_as_uint(f);
    u += 0x7fffu + ((u >> 16) & 1u);          // round-to-nearest-even
    return (unsigned short)(u >> 16);
}
__device__ __forceinline__ void split_bf16(float v, unsigned short& h, unsigned short& l) {
    h = f32_to_bf16(v);
    float hf = __uint_as_float((unsigned)h << 16);
    l = f32_to_bf16(v - hf);
}
// truncating bf16 store type (top 16 bits of fp32; NOT RNE)
struct bf16t { unsigned short u; };
__device__ __forceinline__ void store_act(float* p, float v) { *p = v; }
__device__ __forceinline__ void store_act(unsigned short* p, float v) { *p = f32_to_bf16(v); }
__device__ __forceinline__ void store_act(bf16t* p, float v) {
    p->u = (unsigned short)(__float_as_uint(v) >> 16);
}

template <typename V>
__device__ __forceinline__ bf16x8 pack_b(V r0, V r1) {
    bf16x8 b;
    b[0] = (short)r0[0]; b[1] = (short)r0[1]; b[2] = (short)r0[2]; b[3] = (short)r0[3];
    b[4] = (short)r1[0]; b[5] = (short)r1[1]; b[6] = (short)r1[2]; b[7] = (short)r1[3];
    return b;
}

// ---------------- prep: weight hi/lo split (linear; enc1) ----------------
__global__ __launch_bounds__(256)
void prep_split_w(const float* __restrict__ w, short* __restrict__ whi,
                  short* __restrict__ wlo, long total)
{
    long idx = (long)blockIdx.x * blockDim.x + threadIdx.x;
    if (idx >= total) return;
    unsigned short h, l;
    split_bf16(w[idx], h, l);
    whi[idx] = (short)h; wlo[idx] = (short)l;
}

// Fragment-major hi/lo split for enc2/enc3:
//   whi[((s*MT + m)*64 + l)*8 + kk] = hi(w[co*K + korig])
__global__ __launch_bounds__(256)
void prep_split_w_frag(const float* __restrict__ w, short* __restrict__ whi,
                       short* __restrict__ wlo, int CIN, int COUT)
{
    const int K = CIN * 64;
    const int MT = COUT >> 4;
    long total = (long)COUT * K;
    long idx = (long)blockIdx.x * blockDim.x + threadIdx.x;
    if (idx >= total) return;
    int kk = (int)(idx & 7); long r = idx >> 3;
    int l  = (int)(r & 63);  r >>= 6;
    int m  = (int)(r % MT);
    int s  = (int)(r / MT);
    int n16 = l & 15, quad = l >> 4;
    int co = m * 16 + n16;
    int korig = s * 32 + quad * 8 + kk;
    unsigned short h, lo16;
    split_bf16(w[(long)co * K + korig], h, lo16);
    whi[idx] = (short)h; wlo[idx] = (short)lo16;
}

// ---------------- pad input -> hi/lo bf16 pitched planes --------------------
__global__ __launch_bounds__(256)
void pad_input_split(const float* __restrict__ x, unsigned short* __restrict__ xhi,
                     unsigned short* __restrict__ xlo)
{
    const int D = 64, PD = 66, PRX = 68, BC = 6;
    long total = (long)BC * PD * PD * PRX;
    long idx = (long)blockIdx.x * blockDim.x + threadIdx.x;
    if (idx >= total) return;
    int px = (int)(idx % PRX); long t = idx / PRX;
    int py = (int)(t % PD); t /= PD;
    int pz = (int)(t % PD); int c = (int)(t / PD);
    int ix = px - 1, iy = py - 1, iz = pz - 1;
    float v = 0.0f;
    if ((unsigned)ix < (unsigned)D && (unsigned)iy < (unsigned)D && (unsigned)iz < (unsigned)D)
        v = x[(((long)c * D + iz) * D + iy) * D + ix];
    unsigned short h, l;
    split_bf16(v, h, l);
    xhi[idx] = h; xlo[idx] = l;
}

__global__ __launch_bounds__(256)
void zero_halo_ps(unsigned short* __restrict__ p, int C, int PD, int PRX)
{
    long total = (long)C * PD * PD * PRX;
    long idx = (long)blockIdx.x * blockDim.x + threadIdx.x;
    if (idx >= total) return;
    int px = (int)(idx % PRX); long t = idx / PRX;
    int py = (int)(t % PD); t /= PD;
    int pz = (int)(t % PD);
    if (px == 0 || px >= PD - 1 || py == 0 || py == PD - 1 || pz == 0 || pz == PD - 1)
        p[idx] = 0;
}

template <typename T>
__global__ __launch_bounds__(256) void zero_halo_t(T* __restrict__ p, int C, int PD)
{
    long total = (long)C * PD * PD * PD;
    long idx = (long)blockIdx.x * blockDim.x + threadIdx.x;
    if (idx >= total) return;
    int px = (int)(idx % PD); long t = idx / PD;
    int py = (int)(t % PD); t /= PD;
    int pz = (int)(t % PD);
    if (px == 0 || px == PD - 1 || py == 0 || py == PD - 1 || pz == 0 || pz == PD - 1)
        p[idx] = (T)0;
}

// ---------------------------------------------------------------------------
// Conv3d k4 s2 p1 as MFMA implicit GEMM, bf16 hi/lo pair inputs (enc1 only)
// ---------------------------------------------------------------------------
template <int CIN, int COUT, int DOUT, int PD, int PRX, int MTW, int OWT,
          int OWHALF, int KSPLIT, int OUTSPLIT>
__global__ __launch_bounds__(256)
void conv_s2_mfma(const unsigned short* __restrict__ xhi,
                  const unsigned short* __restrict__ xlo,
                  const short* __restrict__ Whi, const short* __restrict__ Wlo,
                  const float* __restrict__ bias,
                  unsigned short* __restrict__ yhi, unsigned short* __restrict__ ylo,
                  float* __restrict__ yf,
                  int OPD, int OPRX, int po, long sstride)
{
    constexpr int K = CIN * 64;
    constexpr int MWAVES = COUT / (16 * MTW);
    constexpr int RPB = 4 / MWAVES;
    constexpr int KN = (CIN * 2) / KSPLIT;

    int bx = blockIdx.x;
    const int ks = (KSPLIT > 1) ? (bx % KSPLIT) : 0;
    const int rowblk = (KSPLIT > 1) ? (bx / KSPLIT) : bx;
    const int lane = (int)threadIdx.x & 63, w = (int)threadIdx.x >> 6;
    const int mi = (MWAVES == 4) ? w : 0;
    const int ri = (MWAVES == 4) ? 0 : w;
    const int rowid = rowblk * RPB + ri;
    const int n16 = lane & 15, quad = lane >> 4;

    int b, od, oh, ow;
    if (OWHALF) {
        constexpr int NOH = DOUT / 2;
        const int ohb = rowid % NOH; int t = rowid / NOH;
        od = t % DOUT; b = t / DOUT;
        oh = ohb * 2 + (n16 >> 3);
        ow = n16 & 7;
    } else {
        const int owt = rowid % OWT; int t = rowid / OWT;
        oh = t % DOUT; t /= DOUT;
        od = t % DOUT; b = t / DOUT;
        ow = owt * 16 + n16;
    }

    const int co0 = mi * (MTW * 16);

    f32x4 acc[MTW];
    #pragma unroll
    for (int mt = 0; mt < MTW; ++mt)
        #pragma unroll
        for (int r = 0; r < 4; ++r) {
            int co = co0 + mt * 16 + quad * 4 + r;
            acc[mt][r] = (ks == 0) ? bias[co] : 0.0f;
        }

    const int sg0 = ks * KN;
    const long chs = (long)PD * PD * PRX;
    long off = ((long)(b * CIN + (sg0 >> 1)) * PD + (2 * od + (quad >> 1))) * PD * PRX
             + (long)(2 * oh + (quad & 1) * 2) * PRX + 2 * ow;
    const unsigned short* phi = xhi + off;
    const unsigned short* plo = xlo + off;
    const long incA = 2L * PD * PRX;
    const long incB = chs - 2L * PD * PRX;

    const short* a0h = Whi + (long)(co0 + n16) * K + sg0 * 32 + quad * 8;
    const short* a0l = Wlo + (long)(co0 + n16) * K + sg0 * 32 + quad * 8;

    #pragma unroll 2
    for (int s = 0; s < KN; ++s) {
        u16x4u h0 = *(const u16x4u*)phi;
        u16x4u h1 = *(const u16x4u*)(phi + PRX);
        u16x4u l0 = *(const u16x4u*)plo;
        u16x4u l1 = *(const u16x4u*)(plo + PRX);
        bf16x8 bhi = pack_b(h0, h1);
        bf16x8 blo = pack_b(l0, l1);
        #pragma unroll
        for (int mt = 0; mt < MTW; ++mt) {
            bf16x8 ah = *(const bf16x8*)(a0h + (long)mt * 16 * K + s * 32);
            bf16x8 al = *(const bf16x8*)(a0l + (long)mt * 16 * K + s * 32);
            acc[mt] = __builtin_amdgcn_mfma_f32_16x16x32_bf16(ah, bhi, acc[mt], 0, 0, 0);
            acc[mt] = __builtin_amdgcn_mfma_f32_16x16x32_bf16(ah, blo, acc[mt], 0, 0, 0);
            acc[mt] = __builtin_amdgcn_mfma_f32_16x16x32_bf16(al, bhi, acc[mt], 0, 0, 0);
        }
        long inc = (s & 1) ? incB : incA;
        phi += inc; plo += inc;
    }

    if (OUTSPLIT) {
        #pragma unroll
        for (int mt = 0; mt < MTW; ++mt)
            #pragma unroll
            for (int r = 0; r < 4; ++r) {
                int co = co0 + mt * 16 + quad * 4 + r;
                float v = fmaxf(acc[mt][r], 0.0f);
                unsigned short h, l;
                split_bf16(v, h, l);
                long o = (((long)(b * COUT + co) * OPD + od + po) * OPD + oh + po) * OPRX
                       + ow + po;
                yhi[o] = h; ylo[o] = l;
            }
    } else {
        #pragma unroll
        for (int mt = 0; mt < MTW; ++mt)
            #pragma unroll
            for (int r = 0; r < 4; ++r) {
                int co = co0 + mt * 16 + quad * 4 + r;
                long o = (long)ks * sstride
                       + (((long)(b * COUT + co) * OPD + od) * OPD + oh) * OPRX + ow;
                yf[o] = acc[mt][r];
            }
    }
}

// Fragment-direct variant (enc2/enc3): fragment-major Whi/Wlo, each wave
// loads its OWN disjoint (s,m) fragment blocks (coalesced 1KB dwordx4) --
// no LDS, no barriers. Bit-identical to the LDS path.
template <int CIN, int COUT, int DOUT, int PD, int PRX, int MTW, int OWT,
          int OWHALF, int KSPLIT, int OUTSPLIT>
__global__ __launch_bounds__(256)
void conv_s2_mfma_fd(const unsigned short* __restrict__ xhi,
                     const unsigned short* __restrict__ xlo,
                     const short* __restrict__ Whi, const short* __restrict__ Wlo,
                     const float* __restrict__ bias,
                     unsigned short* __restrict__ yhi, unsigned short* __restrict__ ylo,
                     float* __restrict__ yf,
                     int OPD, int OPRX, int po, long sstride)
{
    constexpr int MWAVES = COUT / (16 * MTW);
    constexpr int RPB = 4 / MWAVES;
    constexpr int KN = (CIN * 2) / KSPLIT;
    constexpr int MT = COUT >> 4;            // fragment-major m count
    constexpr int SSTEP = MT * 512;          // shorts per s-step in frag layout

    int bx = blockIdx.x;
    const int ks = (KSPLIT > 1) ? (bx % KSPLIT) : 0;
    const int rowblk = (KSPLIT > 1) ? (bx / KSPLIT) : bx;
    const int lane = (int)threadIdx.x & 63, w = (int)threadIdx.x >> 6;
    const int mi = (MWAVES == 4) ? w : 0;
    const int ri = (MWAVES == 4) ? 0 : w;
    const int rowid = rowblk * RPB + ri;
    const int n16 = lane & 15, quad = lane >> 4;

    int b, od, oh, ow;
    if (OWHALF) {
        constexpr int NOH = DOUT / 2;
        const int ohb = rowid % NOH; int t = rowid / NOH;
        od = t % DOUT; b = t / DOUT;
        oh = ohb * 2 + (n16 >> 3);
        ow = n16 & 7;
    } else {
        const int owt = rowid % OWT; int t = rowid / OWT;
        oh = t % DOUT; t /= DOUT;
        od = t % DOUT; b = t / DOUT;
        ow = owt * 16 + n16;
    }

    const int co0 = mi * (MTW * 16);

    f32x4 acc[MTW];
    #pragma unroll
    for (int mt = 0; mt < MTW; ++mt)
        #pragma unroll
        for (int r = 0; r < 4; ++r) {
            int co = co0 + mt * 16 + quad * 4 + r;
            acc[mt][r] = (ks == 0) ? bias[co] : 0.0f;
        }

    const int sg0 = ks * KN;
    const long chs = (long)PD * PD * PRX;
    long off = ((long)(b * CIN + (sg0 >> 1)) * PD + (2 * od + (quad >> 1))) * PD * PRX
             + (long)(2 * oh + (quad & 1) * 2) * PRX + 2 * ow;
    const unsigned short* phi = xhi + off;
    const unsigned short* plo = xlo + off;
    const long incA = 2L * PD * PRX;
    const long incB = chs - 2L * PD * PRX;

    // fragment-major: (s, m) block at ((s*MT + m)*64 + lane)*8
    const short* ph = Whi + (((long)sg0 * MT + mi * MTW) * 64 + lane) * 8;
    const short* pl = Wlo + (((long)sg0 * MT + mi * MTW) * 64 + lane) * 8;

    #pragma unroll 2
    for (int s = 0; s < KN; ++s) {
        u16x4u h0 = *(const u16x4u*)phi;
        u16x4u h1 = *(const u16x4u*)(phi + PRX);
        u16x4u l0 = *(const u16x4u*)plo;
        u16x4u l1 = *(const u16x4u*)(plo + PRX);
        bf16x8 bhi = pack_b(h0, h1);
        bf16x8 blo = pack_b(l0, l1);
        #pragma unroll
        for (int mt = 0; mt < MTW; ++mt) {
            bf16x8 ah = *(const bf16x8*)(ph + mt * 512);
            bf16x8 al = *(const bf16x8*)(pl + mt * 512);
            acc[mt] = __builtin_amdgcn_mfma_f32_16x16x32_bf16(ah, bhi, acc[mt], 0, 0, 0);
            acc[mt] = __builtin_amdgcn_mfma_f32_16x16x32_bf16(ah, blo, acc[mt], 0, 0, 0);
            acc[mt] = __builtin_amdgcn_mfma_f32_16x16x32_bf16(al, bhi, acc[mt], 0, 0, 0);
        }
        long inc = (s & 1) ? incB : incA;
        phi += inc; plo += inc;
        ph += SSTEP; pl += SSTEP;
    }

    if (OUTSPLIT) {
        #pragma unroll
        for (int mt = 0; mt < MTW; ++mt)
            #pragma unroll
            for (int r = 0; r < 4; ++r) {
                int co = co0 + mt * 16 + quad * 4 + r;
                float v = fmaxf(acc[mt][r], 0.0f);
                unsigned short h, l;
                split_bf16(v, h, l);
                long o = (((long)(b * COUT + co) * OPD + od + po) * OPD + oh + po) * OPRX
                       + ow + po;
                yhi[o] = h; ylo[o] = l;
            }
    } else {
        #pragma unroll
        for (int mt = 0; mt < MTW; ++mt)
            #pragma unroll
            for (int r = 0; r < 4; ++r) {
                int co = co0 + mt * 16 + quad * 4 + r;
                long o = (long)ks * sstride
                       + (((long)(b * COUT + co) * OPD + od) * OPD + oh) * OPRX + ow;
                yf[o] = acc[mt][r];
            }
    }
}

__global__ __launch_bounds__(256)
void combine4_relu(const float* __restrict__ p, float* __restrict__ y, long N, long ss)
{
    long idx = (long)blockIdx.x * blockDim.x + threadIdx.x;
    if (idx >= N) return;
    float v = p[idx] + p[idx + ss] + p[idx + 2 * ss] + p[idx + 3 * ss];
    y[idx] = fmaxf(v, 0.0f);
}

// ---------------- 1x1 conv (fp32 exact) ----------------
__global__ __launch_bounds__(128)
void conv1x1_b(const float* __restrict__ x, const float* __restrict__ w,
               const float* __restrict__ bias, float* __restrict__ y)
{
    const int co = blockIdx.x & 255, b = blockIdx.x >> 8;
    const int s4 = (int)threadIdx.x * 4;
    const float* xb = x + (long)b * 256 * 512 + s4;
    const float* wr = w + (long)co * 256;      // uniform -> s_load
    float bv = bias[co];
    float4 acc = {bv, bv, bv, bv};
    for (int ci = 0; ci < 256; ++ci) {
        float wv = wr[ci];
        float4 xv = *(const float4*)(xb + (long)ci * 512);
        acc.x = fmaf(xv.x, wv, acc.x); acc.y = fmaf(xv.y, wv, acc.y);
        acc.z = fmaf(xv.z, wv, acc.z); acc.w = fmaf(xv.w, wv, acc.w);
    }
    *(float4*)(y + (long)(b * 256 + co) * 512 + s4) = acc;
}

// ---------------- VQ (fp32 exact) ----------------
__global__ void codenorm_kernel(const float* __restrict__ cb, float* __restrict__ norms)
{
    int k = blockIdx.x;
    int lane = threadIdx.x;
    float s = 0.0f;
    const float* row = cb + (long)k * 256;
    for (int d = lane; d < 256; d += 64) { float v = row[d]; s = fmaf(v, v, s); }
    for (int off = 32; off > 0; off >>= 1) s += __shfl_down(s, off);
    if (lane == 0) norms[k] = s;
}

// cbT[d*1024 + k] = cb[k*256 + d]  (fp32 copy -> values unchanged)
__global__ __launch_bounds__(256)
void transpose_cb(const float* __restrict__ cb, float* __restrict__ cbT)
{
    int idx = blockIdx.x * 256 + (int)threadIdx.x;    // 0..262143
    int d = idx & 255, k = idx >> 8;
    cbT[(long)d * 1024 + k] = cb[(long)k * 256 + d];
}

// R24: 4 rows/block (grid 256), coalesced cbT float4 loads (codes 4t..4t+3),
// rows staged in LDS. Bit-identical to the original per-row kernel.
__global__ __launch_bounds__(256)
void vq_kernel4(const float* __restrict__ lat, const float* __restrict__ cb,
                const float* __restrict__ cbT, const float* __restrict__ norms,
                unsigned short* __restrict__ q, float* __restrict__ idx_out)
{
    __shared__ __align__(16) float rows[4][256];
    __shared__ float s_best[4][256];
    __shared__ int   s_bidx[4][256];
    const int r0 = blockIdx.x * 4;
    const int t = (int)threadIdx.x;

    #pragma unroll
    for (int j = 0; j < 4; ++j)
        rows[j][t] = lat[(long)(r0 + j) * 256 + t];
    __syncthreads();

    // latn per row -- identical float4 fmaf chain to the original
    float latn[4];
    #pragma unroll
    for (int j = 0; j < 4; ++j) {
        const float4* rowv = (const float4*)rows[j];
        float a = 0.0f;
        #pragma unroll 4
        for (int d = 0; d < 64; ++d) {
            float4 rv = rowv[d];
            a = fmaf(rv.x, rv.x, a); a = fmaf(rv.y, rv.y, a);
            a = fmaf(rv.z, rv.z, a); a = fmaf(rv.w, rv.w, a);
        }
        latn[j] = a;
    }

    // codes 4t..4t+3; dot[j][c] accumulates d = 0..255 sequentially (same
    // chain as the original scalar loop)
    float dot[4][4] = {};
    const float* ct = cbT + t * 4;
    #pragma unroll 4
    for (int d = 0; d < 256; ++d) {
        float4 c4 = *(const float4*)(ct + (long)d * 1024);
        #pragma unroll
        for (int j = 0; j < 4; ++j) {
            float rv = rows[j][d];
            dot[j][0] = fmaf(rv, c4.x, dot[j][0]);
            dot[j][1] = fmaf(rv, c4.y, dot[j][1]);
            dot[j][2] = fmaf(rv, c4.z, dot[j][2]);
            dot[j][3] = fmaf(rv, c4.w, dot[j][3]);
        }
    }

    float4 nv = *(const float4*)(norms + t * 4);
    float nr[4] = {nv.x, nv.y, nv.z, nv.w};

    #pragma unroll
    for (int j = 0; j < 4; ++j) {
        float best = FLT_MAX;
        int bidx = 0x7fffffff;
        #pragma unroll
        for (int c = 0; c < 4; ++c) {
            float sc = latn[j] - 2.0f * dot[j][c] + nr[c];
            int k = t * 4 + c;
            if (sc < best || (sc == best && k < bidx)) { best = sc; bidx = k; }
        }
        s_best[j][t] = best; s_bidx[j][t] = bidx;
    }
    __syncthreads();
    for (int off = 128; off > 0; off >>= 1) {
        if (t < off) {
            #pragma unroll
            for (int j = 0; j < 4; ++j) {
                float o = s_best[j][t + off]; int oi = s_bidx[j][t + off];
                if (o < s_best[j][t] || (o == s_best[j][t] && oi < s_bidx[j][t])) {
                    s_best[j][t] = o; s_bidx[j][t] = oi;
                }
            }
        }
        __syncthreads();
    }

    #pragma unroll
    for (int j = 0; j < 4; ++j) {
        const int bk = s_bidx[j][0];
        const int r = r0 + j;
        const int b = r >> 9, n = r & 511;
        const int zz = n >> 6, yy = (n >> 3) & 7, xx = n & 7;
        q[(long)(b * 256 + t) * 1000 + ((long)(zz + 1) * 10 + (yy + 1)) * 10 + (xx + 1)]
            = f32_to_bf16(cb[(long)bk * 256 + t]);
    }
    if (t == 0) {
        #pragma unroll
        for (int j = 0; j < 4; ++j)
            idx_out[r0 + j] = (float)s_bidx[j][0];
    }
}

// ---------------- decoder: MFMA implicit-GEMM ConvTranspose ----------------
// xflip=0: B slot a <-> x offset (1-ax), kw=(1-px)+2*ax (old cube kernel).
// xflip=1: B slot a <-> x offset ax,     kw=(1-px)+2*(1-ax) (dword-pair kernel).
__global__ __launch_bounds__(256)
void prep_convt_w(const float* __restrict__ w, short* __restrict__ Ap,
                  int Cin, int Cout, int xflip)
{
    const int K = Cin * 8;
    long total = 8L * Cout * K;
    long idx = (long)blockIdx.x * blockDim.x + threadIdx.x;
    if (idx >= total) return;
    int k = (int)(idx % K);
    int co = (int)((idx / K) % Cout);
    int p = (int)(idx / ((long)K * Cout));
    int ci = k >> 3, a = k & 7;
    int az = (a >> 2) & 1, ay = (a >> 1) & 1, ax = a & 1;
    int pz = p >> 2, py = (p >> 1) & 1, px = p & 1;
    int axw = xflip ? (1 - ax) : ax;
    int kd = (1 - pz) + 2 * az, kh = (1 - py) + 2 * ay, kw = (1 - px) + 2 * axw;
    float v = w[((long)ci * Cout + co) * 64 + kd * 16 + kh * 4 + kw];
    Ap[idx] = (short)f32_to_bf16(v);
}

// Fragment-major layout for the LDS-staged v2 kernel:
//   ApN[((p*MG + mg)*nsteps + s)*2048 + cb*512 + l*8 + kk]
__global__ __launch_bounds__(256)
void prep_convt_w_frag(const float* __restrict__ w, short* __restrict__ Ap,
                       int Cin, int Cout, int xflip)
{
    const int MG = Cout >> 6;
    const int nsteps = Cin >> 2;             // (Cin*8)/32
    long total = 8L * MG * nsteps * 2048;
    long idx = (long)blockIdx.x * blockDim.x + threadIdx.x;
    if (idx >= total) return;
    int kk = (int)(idx & 7); long r = idx >> 3;
    int l  = (int)(r & 63);  r >>= 6;
    int cb = (int)(r & 3);   r >>= 2;
    int s  = (int)(r % nsteps); r /= nsteps;
    int mg = (int)(r % MG);
    int p  = (int)(r / MG);

    int n16 = l & 15, quad = l >> 4;
    int korig = s * 32 + quad * 8 + kk;
    int co = mg * 64 + cb * 16 + n16;
    int ci = korig >> 3, a = korig & 7;
    int az = (a >> 2) & 1, ay = (a >> 1) & 1, ax = a & 1;
    int pz = p >> 2, py = (p >> 1) & 1, px = p & 1;
    int axw = xflip ? (1 - ax) : ax;
    int kd = (1 - pz) + 2 * az, kh = (1 - py) + 2 * ay, kw = (1 - px) + 2 * axw;
    float v = w[((long)ci * Cout + co) * 64 + kd * 16 + kh * 4 + kw];
    Ap[idx] = (short)f32_to_bf16(v);
}

// Old cube-N layout (kept for dec1, DIN=8): round-0 body.
template <int CIN, int COUT, int DIN, int OPAD, typename OutT>
__global__ __launch_bounds__(256)
void convt_mfma(const unsigned short* __restrict__ Xp, const short* __restrict__ Ap,
                const float* __restrict__ bias, OutT* __restrict__ Y)
{
    constexpr int PD = DIN + 2;
    constexpr int PD3 = PD * PD * PD;
    constexpr int T = DIN >> 2;
    constexpr int NT = T * T * T;
    constexpr int SLAB = NT / 8;
    constexpr int OPD = 2 * DIN + 2 * OPAD;
    constexpr int K = CIN * 8;
    constexpr int MG = COUT >> 6;
    constexpr int nsteps = K >> 5;

    int bx = blockIdx.x;
    const int xcd = bx & 7;
    int local = bx >> 3;
    const int px = local & 1; local >>= 1;
    const int mg = local % MG; local /= MG;
    const int ntin = local % SLAB;
    const int pzy = local / SLAB;            // 0..3
    const int pz = pzy >> 1, py = pzy & 1;
    const int p = pz * 4 + py * 2 + px;
    const int nt = xcd * SLAB + ntin;

    const int lane = threadIdx.x & 63, wave = threadIdx.x >> 6;
    const int n16 = lane & 15, quad = lane >> 4;

    const int tx = nt % T, ty = (nt / T) % T, tz = nt / (T * T);
    const int mz = tz * 4 + wave, my = ty * 4 + (n16 >> 2), mx = tx * 4 + (n16 & 3);
    const int sp = ((mz + pz) * PD + (my + py)) * PD + (mx + px);

    const unsigned short* xq = Xp + (long)quad * PD3 + sp;

    const int cobase = mg * 64;
    const short* ap0 = Ap + ((long)p * COUT + cobase + n16) * K + quad * 8;

    f32x4 acc[4];
    #pragma unroll
    for (int cb = 0; cb < 4; ++cb) {
        const float* bp = bias + cobase + cb * 16 + quad * 4;
        acc[cb][0] = bp[0]; acc[cb][1] = bp[1]; acc[cb][2] = bp[2]; acc[cb][3] = bp[3];
    }

    #pragma unroll 4
    for (int s = 0; s < nsteps; ++s) {
        const unsigned short* xs = xq + (long)s * 4 * PD3;
        bf16x8 bf;
        bf[0] = (short)xs[(PD + 1) * PD + 1];
        bf[1] = (short)xs[(PD + 1) * PD];
        bf[2] = (short)xs[PD * PD + 1];
        bf[3] = (short)xs[PD * PD];
        bf[4] = (short)xs[PD + 1];
        bf[5] = (short)xs[PD];
        bf[6] = (short)xs[1];
        bf[7] = (short)xs[0];
        #pragma unroll
        for (int cb = 0; cb < 4; ++cb) {
            bf16x8 af = *(const bf16x8*)(ap0 + (long)cb * 16 * K + s * 32);
            acc[cb] = __builtin_amdgcn_mfma_f32_16x16x32_bf16(af, bf, acc[cb], 0, 0, 0);
        }
    }

    const int opz = 2 * mz + pz + OPAD, opy = 2 * my + py + OPAD, opx = 2 * mx + px + OPAD;
    const long spo = ((long)opz * OPD + opy) * OPD + opx;
    #pragma unroll
    for (int cb = 0; cb < 4; ++cb) {
        #pragma unroll
        for (int r = 0; r < 4; ++r) {
            int co = cobase + cb * 16 + quad * 4 + r;
            float v = fmaxf(acc[cb][r], 0.0f);
            store_act(Y + (long)co * OPD * OPD * OPD + spo, v);
        }
    }
}

// Dword-pair B-gather (dec2/dec3), R29: 2 K-steps per barrier phase.
// Per-acc MFMA order = old sequential s => bit-identical.
template <int CIN, int COUT, int DIN, int OPAD, int MXP, int MYP, typename OutT>
__global__ __launch_bounds__(256)
void convt_mfma_v2(const unsigned short* __restrict__ Xp, const short* __restrict__ Ap,
                   const float* __restrict__ bias, OutT* __restrict__ Y)
{
    constexpr int PD = DIN + 2;
    constexpr int PD3 = PD * PD * PD;
    constexpr int OPD = 2 * DIN + 2 * OPAD;
    constexpr int K = CIN * 8;
    constexpr int MG = COUT >> 6;
    constexpr int nsteps = K >> 5;
    static_assert((nsteps & 1) == 0 && nsteps >= 4, "phase merge needs even nsteps");
    constexpr int NPH = nsteps / 2;
    constexpr int MXT = DIN / (16 * MXP);
    constexpr int MYT = DIN / (4 * MYP);
    constexpr int MZS = DIN / 8;             // mz per XCD slab
    constexpr int TPE = MXP * MYP;           // tiles per wave (one of MXP/MYP is 1)

    int bx = blockIdx.x;
    const int xcd = bx & 7;
    int local = bx >> 3;
    const int px = local & 1; local >>= 1;
    const int py = local & 1; local >>= 1;
    const int mg = local % MG; local /= MG;
    const int mxt = local % MXT; local /= MXT;
    const int myt = local % MYT; local /= MYT;
    const int pz = local & 1; local >>= 1;
    const int mzin = local;                  // 0..MZS-1
    const int mz = xcd * MZS + mzin;
    const int p = pz * 4 + py * 2 + px;

    const int lane = threadIdx.x & 63, wave = threadIdx.x >> 6;
    const int n16 = lane & 15, quad = lane >> 4;

    const int mx0 = mxt * (16 * MXP) + n16;
    const int my0 = myt * (4 * MYP) + wave * MYP;
    const int baseX = mx0 & ~1;
    const int sh = 16 * ((n16 & 1) + px);    // 0, 16, or 32
    const long sp = ((long)(mz + pz) * PD + (my0 + py)) * PD + baseX;

    const unsigned short* xq = Xp + (long)quad * PD3 + sp;

    // fragment-major weight tiles: 2048 shorts (4KB) per (p,mg,s)
    const short* ApT = Ap + (((long)p * MG + mg) * nsteps) * 2048;

    __shared__ short Abuf[2][2][2048];       // 16KB: dbuf x 2-steps x 4KB

    f32x4 acc[TPE][4];
    #pragma unroll
    for (int t = 0; t < TPE; ++t)
        #pragma unroll
        for (int cb = 0; cb < 4; ++cb) {
            const float* bp = bias + (mg * 64) + cb * 16 + quad * 4;
            acc[t][cb][0] = bp[0]; acc[t][cb][1] = bp[1];
            acc[t][cb][2] = bp[2]; acc[t][cb][3] = bp[3];
        }

    constexpr int rowoff[4] = { (PD + 1) * PD, PD * PD, PD, 0 };
    union Frag { unsigned u[4]; bf16x8 b; };

    const int chunkoff = wave * 512 + lane * 8;   // this thread's 16B of a 4KB tile

    // prologue: stage steps 0 and 1
    {
        *(bf16x8*)(&Abuf[0][0][chunkoff]) = *(const bf16x8*)(ApT + chunkoff);
        *(bf16x8*)(&Abuf[0][1][chunkoff]) = *(const bf16x8*)(ApT + 2048 + chunkoff);
    }
    __syncthreads();

    #pragma unroll 1
    for (int ph = 0; ph < NPH; ++ph) {
        const int cur = ph & 1;
        const bool more = (ph + 1 < NPH);
        bf16x8 an0, an1;
        if (more) {
            an0 = *(const bf16x8*)(ApT + (long)(2 * ph + 2) * 2048 + chunkoff);
            an1 = *(const bf16x8*)(ApT + (long)(2 * ph + 3) * 2048 + chunkoff);
        }

        // X loads for both steps (raw staging; 2x loads in flight)
        unsigned long long xr[2][TPE][4];
        #pragma unroll
        for (int u = 0; u < 2; ++u) {
            const unsigned short* xs = xq + (long)(2 * ph + u) * 4 * PD3;
            #pragma unroll
            for (int t = 0; t < TPE; ++t) {
                const int toff = (MXP > 1) ? t * 16 : t * PD;
                #pragma unroll
                for (int j = 0; j < 4; ++j) {
                    union { u16x4u v; unsigned long long u64; } ld;
                    ld.v = *(const u16x4u*)(xs + toff + rowoff[j]);
                    xr[u][t][j] = ld.u64;
                }
            }
        }

        // A fragments from LDS for both steps
        bf16x8 af[2][4];
        #pragma unroll
        for (int u = 0; u < 2; ++u)
            #pragma unroll
            for (int cb = 0; cb < 4; ++cb)
                af[u][cb] = *(const bf16x8*)(&Abuf[cur][u][cb * 512 + lane * 8]);

        // MFMA: step 2ph then 2ph+1 (old sequential order)
        #pragma unroll
        for (int u = 0; u < 2; ++u) {
            #pragma unroll
            for (int t = 0; t < TPE; ++t) {
                Frag fr;
                #pragma unroll
                for (int j = 0; j < 4; ++j)
                    fr.u[j] = (unsigned)(xr[u][t][j] >> sh);
                #pragma unroll
                for (int cb = 0; cb < 4; ++cb)
                    acc[t][cb] = __builtin_amdgcn_mfma_f32_16x16x32_bf16(af[u][cb], fr.b,
                                                                         acc[t][cb], 0, 0, 0);
            }
        }

        if (more) {
            *(bf16x8*)(&Abuf[cur ^ 1][0][chunkoff]) = an0;
            *(bf16x8*)(&Abuf[cur ^ 1][1][chunkoff]) = an1;
        }
        __syncthreads();
    }

    const int opz = 2 * mz + pz + OPAD;
    #pragma unroll
    for (int t = 0; t < TPE; ++t) {
        const int opx = 2 * (mx0 + ((MXP > 1) ? t * 16 : 0)) + px + OPAD;
        const int opy = 2 * (my0 + ((MYP > 1) ? t : 0)) + py + OPAD;
        const long spo = ((long)opz * OPD + opy) * OPD + opx;
        #pragma unroll
        for (int cb = 0; cb < 4; ++cb) {
            #pragma unroll
            for (int r = 0; r < 4; ++r) {
                int co = (mg * 64) + cb * 16 + quad * 4 + r;
                float v = fmaxf(acc[t][cb][r], 0.0f);
                store_act(Y + (long)co * OPD * OPD * OPD + spo, v);
            }
        }
    }
}

// ---------------- dec4 as MFMA GEMM, R30: bf16 d3 input ----------------
// Fragment-major: Aw[(s*64 + lane)*8 + kk] (unchanged from R23).
__global__ __launch_bounds__(256)
void prep_dec4A_frag(const float* __restrict__ w, short* __restrict__ Aw)
{
    int idx = blockIdx.x * 256 + (int)threadIdx.x;    // 0..65535
    int kk = idx & 7;
    int l  = (idx >> 3) & 63;
    int s  = idx >> 9;                                // 0..127
    int n16 = l & 15, quad = l >> 4;
    int k = s * 32 + quad * 8 + kk;
    float v = (n16 < 3) ? w[n16 * 4096 + k] : 0.0f;
    Aw[idx] = (short)f32_to_bf16(v);
}

// R30: d3 truncated-bf16 (ushort); Xs ushort[2][28][80]; RS=80 read windows
// {0,16,24,8} (free); strided staging (64 consecutive shorts/wave-pass).
// Fragment words rebuilt via 64-bit shifts: bit-identical.
__global__ __launch_bounds__(256)
void conv_dec4_mfma(const unsigned short* __restrict__ d3h, const short* __restrict__ Aw,
                    const float* __restrict__ bias, float* __restrict__ y)
{
    constexpr int D = 64, Dout = 61;
    constexpr int RS = 80;                 // row stride (shorts)
    int bx = blockIdx.x;
    const int slab = bx & 7;
    const int i = bx >> 3;                 // 0..127
    const int od = slab * 8 + (i >> 4);
    const int oh0 = (i & 15) * 4;          // covers oh0..oh0+3 (guard < 61)
    if (od >= Dout) return;                // uniform per block -> barriers safe
    const int tid = (int)threadIdx.x;
    const int lane = tid & 63, wave = tid >> 6;
    const int n16 = lane & 15, quad = lane >> 4;
    const int ow = wave * 16 + n16;

    __shared__ unsigned short Xs[2][28][RS];
    unsigned short* xsb = &Xs[0][0][0];
    constexpr int BUFW = 28 * RS;          // shorts per buffer

    f32x4 acc[4];
    #pragma unroll
    for (int j = 0; j < 4; ++j)
        #pragma unroll
        for (int r = 0; r < 4; ++r) {
            int co = quad * 4 + r;
            acc[j][r] = (co < 3) ? bias[co] : 0.0f;
        }

    const int kd0 = quad >> 1;
    const int kh0 = (quad & 1) * 2;
    const int sha = 16 * (ow & 1);
    const int owb = ow & ~1;

    const bool sact = (tid < 224);
    int goff[8];                           // global short offset (ci-invariant)
    int loff[8];                           // LDS short offset within a buffer
    #pragma unroll
    for (int j = 0; j < 8; ++j) {
        const int g = tid + 224 * j;
        const int row = g >> 6, xx = g & 63;
        const int szi = row / 7, syi = row % 7;
        goff[j] = ((od + szi) * D + min(oh0 + syi, D - 1)) * D + xx;
        loff[j] = row * RS + xx;
    }
    auto choff = [](int S) { return (long)S * D * D * D; };

    if (sact) {
        #pragma unroll
        for (int j = 0; j < 8; ++j)
            xsb[loff[j]] = d3h[goff[j]];
    }
    __syncthreads();

    #pragma unroll 1
    for (int S = 0; S < 64; ++S) {
        const int cur = S & 1;
        const bool more = (S + 1 < 64);
        unsigned short nv[8];
        if (more && sact) {
            const unsigned short* src = d3h + choff(S + 1);
            #pragma unroll
            for (int j = 0; j < 8; ++j)
                nv[j] = src[goff[j]];
        }

        #pragma unroll
        for (int h = 0; h < 2; ++h) {
            bf16x8 af = *(const bf16x8*)(Aw + ((long)(2 * S + h) * 64 + lane) * 8);
            unsigned p0[5], p1[5];
            #pragma unroll
            for (int r = 0; r < 5; ++r) {
                const int row = 14 * h + kd0 * 7 + kh0 + r;
                union { u16x8a4 v; unsigned long long q[2]; } ld;
                ld.v = *(const u16x8a4*)(xsb + cur * BUFW + row * RS + owb);
                p0[r] = (unsigned)(ld.q[0] >> sha);
                p1[r] = (unsigned)(((ld.q[0] >> 32) | (ld.q[1] << 32)) >> sha);
            }
            #pragma unroll
            for (int j = 0; j < 4; ++j) {
                union { unsigned u[4]; bf16x8 b; } fr;
                fr.u[0] = p0[j];     fr.u[1] = p1[j];
                fr.u[2] = p0[j + 1]; fr.u[3] = p1[j + 1];
                acc[j] = __builtin_amdgcn_mfma_f32_16x16x32_bf16(af, fr.b, acc[j], 0, 0, 0);
            }
        }

        if (more && sact) {
            unsigned short* dst = xsb + (cur ^ 1) * BUFW;
            #pragma unroll
            for (int j = 0; j < 8; ++j)
                dst[loff[j]] = nv[j];
        }
        __syncthreads();
    }

    if (ow < Dout && quad == 0) {
        #pragma unroll
        for (int j = 0; j < 4; ++j) {
            const int oh = oh0 + j;
            if (oh >= Dout) continue;
            #pragma unroll
            for (int r = 0; r < 3; ++r)
                y[((long)(r * Dout + od) * Dout + oh) * Dout + ow] = tanhf(acc[j][r]);
        }
    }
}

extern "C" void kernel_launch(void* const* d_in, const int* in_sizes, int n_in,
                              void* d_out, int out_size, void* d_ws, size_t ws_size,
                              hipStream_t stream)
{
    const float* x        = (const float*)d_in[0];
    const float* enc_w1   = (const float*)d_in[1];
    const float* enc_b1   = (const float*)d_in[2];
    const float* enc_w2   = (const float*)d_in[3];
    const float* enc_b2   = (const float*)d_in[4];
    const float* enc_w3   = (const float*)d_in[5];
    const float* enc_b3   = (const float*)d_in[6];
    const float* enc_w4   = (const float*)d_in[7];
    const float* enc_b4   = (const float*)d_in[8];
    const float* codebook = (const float*)d_in[9];
    const float* dec_w1   = (const float*)d_in[10];
    const float* dec_b1   = (const float*)d_in[11];
    const float* dec_w2   = (const float*)d_in[12];
    const float* dec_b2   = (const float*)d_in[13];
    const float* dec_w3   = (const float*)d_in[14];
    const float* dec_b3   = (const float*)d_in[15];
    const float* dec_w4   = (const float*)d_in[16];
    const float* dec_b4   = (const float*)d_in[17];

    float* out = (float*)d_out;
    float* idx_out = out + 2L * 3 * 61 * 61 * 61;

    // ---- workspace (byte offsets) ----
    char* wsb = (char*)d_ws;
    float*          cn   = (float*)wsb;                        //      4,096
    unsigned short* qp   = (unsigned short*)(wsb + 4096);      //  1,024,000
    short*          Ap1  = (short*)(wsb + 1028096);            //  8,388,608
    short*          Ap2  = (short*)(wsb + 9416704);            //  4,194,304
    short*          Ap3  = (short*)(wsb + 13611008);           //  1,048,576
    short*          Aw4  = (short*)(wsb + 14659584);           //    131,072
    short*          W1hi = (short*)(wsb + 14790656);           //     24,576
    short*          W1lo = (short*)(wsb + 14815232);           //     24,576
    short*          W2hi = (short*)(wsb + 14839808);           //  1,048,576
    short*          W2lo = (short*)(wsb + 15888384);           //  1,048,576
    short*          W3hi = (short*)(wsb + 16936960);           //  4,194,304
    short*          W3lo = (short*)(wsb + 21131264);           //  4,194,304
    char* arena = wsb + 25325568;
    // encoder phase:
    unsigned short* xphi = (unsigned short*)arena;                    // (2,3,66,66,68)
    unsigned short* xplo = (unsigned short*)(arena + 3554496);
    unsigned short* h1hi = (unsigned short*)(arena + 7108992);        // (2,64,34,34,36)
    unsigned short* h1lo = (unsigned short*)(arena + 17762688);
    unsigned short* h2hi = (unsigned short*)(arena + 28416384);       // (2,128,18,18,20)
    unsigned short* h2lo = (unsigned short*)(arena + 31734144);
    float*          pp3  = (float*)(arena + 35051904);                // 4x(2,256,8^3)
    float*          h3   = (float*)(arena + 39246208);                // (2,256,512)
    float*          lat  = (float*)(arena + 40294784);                // (2,256,512)
    // decoder phase (after VQ; overlaps encoder buffers):
    unsigned short* d1 = (unsigned short*)arena;                      // (256,18^3) bf16
    unsigned short* d2 = (unsigned short*)(arena + 2985984);          // (128,34^3) bf16
    bf16t*          d3 = (bf16t*)(arena + 13047808);                  // (64,64^3) bf16-trunc
    // arena peak < 80.2 MB -> ws used 105.5 MB; cbT appended below:
    float*          cbT = (float*)(wsb + 105482240);                  // 1,048,576
    // total 106.5 MB (< 112.2 MB proven in R0)

    dim3 blk(256);
    auto nblk = [](long n) { return dim3((unsigned)((n + 255) / 256)); };

    // ---- weight prep ----
    prep_convt_w<<<nblk(8L * 256 * 2048), blk, 0, stream>>>(dec_w1, Ap1, 256, 256, 0);
    prep_convt_w_frag<<<nblk(8L * 128 * 2048), blk, 0, stream>>>(dec_w2, Ap2, 256, 128, 1);
    prep_convt_w_frag<<<nblk(8L * 64 * 1024), blk, 0, stream>>>(dec_w3, Ap3, 128, 64, 1);
    prep_dec4A_frag<<<dim3(256), blk, 0, stream>>>(dec_w4, Aw4);
    prep_split_w<<<nblk(12288), blk, 0, stream>>>(enc_w1, W1hi, W1lo, 12288);
    prep_split_w_frag<<<nblk(524288), blk, 0, stream>>>(enc_w2, W2hi, W2lo, 64, 128);
    prep_split_w_frag<<<nblk(2097152), blk, 0, stream>>>(enc_w3, W3hi, W3lo, 128, 256);
    transpose_cb<<<dim3(1024), blk, 0, stream>>>(codebook, cbT);

    // ---- encoder (MFMA, bf16-pair) ----
    pad_input_split<<<nblk(6L * 66 * 66 * 68), blk, 0, stream>>>(x, xphi, xplo);
    zero_halo_ps<<<nblk(128L * 34 * 34 * 36), blk, 0, stream>>>(h1hi, 128, 34, 36);
    zero_halo_ps<<<nblk(128L * 34 * 34 * 36), blk, 0, stream>>>(h1lo, 128, 34, 36);
    conv_s2_mfma<3, 64, 32, 66, 68, 4, 2, 0, 1, 1><<<dim3(1024), blk, 0, stream>>>(
        xphi, xplo, W1hi, W1lo, enc_b1, h1hi, h1lo, nullptr, 34, 36, 1, 0);
    zero_halo_ps<<<nblk(256L * 18 * 18 * 20), blk, 0, stream>>>(h2hi, 256, 18, 20);
    zero_halo_ps<<<nblk(256L * 18 * 18 * 20), blk, 0, stream>>>(h2lo, 256, 18, 20);
    conv_s2_mfma_fd<64, 128, 16, 34, 36, 2, 1, 0, 1, 1><<<dim3(512), blk, 0, stream>>>(
        h1hi, h1lo, W2hi, W2lo, enc_b2, h2hi, h2lo, nullptr, 18, 20, 1, 0);
    conv_s2_mfma_fd<128, 256, 8, 18, 20, 4, 1, 1, 4, 0><<<dim3(256), blk, 0, stream>>>(
        h2hi, h2lo, W3hi, W3lo, enc_b3, nullptr, nullptr, pp3, 8, 8, 0, 262144);
    combine4_relu<<<nblk(262144), blk, 0, stream>>>(pp3, h3, 262144, 262144);
    conv1x1_b<<<dim3(512), dim3(128), 0, stream>>>(h3, enc_w4, enc_b4, lat);

    // ---- VQ (fp32 exact) ----
    codenorm_kernel<<<dim3(1024), dim3(64), 0, stream>>>(codebook, cn);
    zero_halo_t<unsigned short><<<nblk(512L * 10 * 10 * 10), blk, 0, stream>>>(qp, 512, 10);
    vq_kernel4<<<dim3(256), blk, 0, stream>>>(lat, codebook, cbT, cn, qp, idx_out);

    // ---- decoder halos ----
    zero_halo_t<unsigned short><<<nblk(256L * 18 * 18 * 18), blk, 0, stream>>>(d1, 256, 18);
    zero_halo_t<unsigned short><<<nblk(128L * 34 * 34 * 34), blk, 0, stream>>>(d2, 128, 34);

    // ---- decoder (MFMA) per batch ----
    for (int b = 0; b < 2; ++b) {
        const unsigned short* qb = qp + (long)b * 256 * 1000;
        float* outb = out + (long)b * 3 * 226981;
        // dec1 (DIN=8, old layout): grid = 8*2*4*1*4 = 256
        convt_mfma<256, 256, 8, 1, unsigned short><<<dim3(256), blk, 0, stream>>>(
            qb, Ap1, dec_b1, d1);
        // dec2 (v2, MXP=1 MYP=2): grid = 8 * (2*2*2*1*2*2*2) = 512
        convt_mfma_v2<256, 128, 16, 1, 1, 2, unsigned short><<<dim3(512), blk, 0, stream>>>(
            d1, Ap2, dec_b2, d2);
        // dec3 (v2, MXP=2 MYP=1): grid = 8 * (2*2*1*1*8*2*4) = 2048, bf16t out
        convt_mfma_v2<128, 64, 32, 0, 2, 1, bf16t><<<dim3(2048), blk, 0, stream>>>(
            d2, Ap3, dec_b3, d3);
        conv_dec4_mfma<<<dim3(8 * 8 * 16), blk, 0, stream>>>(
            (const unsigned short*)d3, Aw4, dec_b4, outb);
    }
}